// Round 3
// baseline (292.124 us; speedup 1.0000x reference)
//
#include <hip/hip_runtime.h>
#include <math.h>

#define LN 4096
#define CN 64
#define BQ 32
#define NTH 256

// ws offsets (floats)
#define OFF_CHAN_SUM   0        // 2048
#define OFF_CHAN_JERK  2048     // 2048
#define OFF_CHAN_JRATE 4096     // 2048
#define OFF_CHAN_ZCR   6144     // 2048
#define OFF_SVMST      8192     // 32*16 per-b stat accumulators
#define OFF_SPEC       8704     // 32*3
#define OFF_EFF_B      8800     // 2048
#define OFF_GN         10848    // 64 doubles = 128 floats (byte off 43392 %8==0)
#define OFF_EFF_W      10976    // 2048*64
#define OFF_SVMBUF     142048   // 32*4096

// ---------------- K0: zero atomic accumulators ----------------
__global__ void k0_zero(float* __restrict__ ws) {
  int t = threadIdx.x;
  if (t < 512) ws[OFF_SVMST + t] = 0.f;
  if (t < 96)  ws[OFF_SPEC + t] = 0.f;
  if (t < 128) ws[OFF_GN + t] = 0.f;
}

// ---------------- K1: per-(b,c) scans, register chunks + shuffle reduce ----------------
__global__ __launch_bounds__(NTH) void k1_chan(const float* __restrict__ x, float* __restrict__ ws) {
  int bc = blockIdx.x;
  const float* row = x + (size_t)bc * LN;
  int t = threadIdx.x;
  int l0 = t * 16;
  float rd[18];
  const float4* r4 = (const float4*)(row + l0);
#pragma unroll
  for (int q = 0; q < 4; q++) {
    float4 v = r4[q];
    rd[4*q] = v.x; rd[4*q+1] = v.y; rd[4*q+2] = v.z; rd[4*q+3] = v.w;
  }
  if (t < 255) { rd[16] = row[l0 + 16]; rd[17] = row[l0 + 17]; }
  else { rd[16] = 0.f; rd[17] = 0.f; }
  float lsum = 0.f, jm = 0.f, jrm = 0.f; int zc = 0;
#pragma unroll
  for (int i = 0; i < 16; i++) {
    float a = rd[i], b2 = rd[i+1];
    lsum += a;
    int l = l0 + i;
    if (l < LN - 1) {
      jm = fmaxf(jm, fabsf(b2 - a));
      zc += (a * b2 < 0.f);
      if (l < LN - 2) jrm = fmaxf(jrm, fabsf(rd[i+2] - 2.f*b2 + a));
    }
  }
  for (int off = 32; off > 0; off >>= 1) {
    lsum += __shfl_down(lsum, off);
    jm = fmaxf(jm, __shfl_down(jm, off));
    jrm = fmaxf(jrm, __shfl_down(jrm, off));
    zc += __shfl_down(zc, off);
  }
  __shared__ float s1[4], s2_[4], s3[4]; __shared__ int s4[4];
  int w = t >> 6;
  if ((t & 63) == 0) { s1[w] = lsum; s2_[w] = jm; s3[w] = jrm; s4[w] = zc; }
  __syncthreads();
  if (t == 0) {
    float S = 0, J = 0, JR = 0; int Z = 0;
    for (int i = 0; i < 4; i++) { S += s1[i]; J = fmaxf(J, s2_[i]); JR = fmaxf(JR, s3[i]); Z += s4[i]; }
    ws[OFF_CHAN_SUM + bc]   = S;
    ws[OFF_CHAN_JERK + bc]  = J * 50.f;
    ws[OFF_CHAN_JRATE + bc] = JR * 2500.f;
    ws[OFF_CHAN_ZCR + bc]   = (float)Z;
  }
}

// ---------------- KA: svm + partial stats (512 blocks) ----------------
__global__ __launch_bounds__(NTH) void kA_svm(const float* __restrict__ x, float* __restrict__ ws) {
  int blk = blockIdx.x;            // b*16 + lt
  int b = blk >> 4, lt = blk & 15;
  int t = threadIdx.x;
  int l = lt * 256 + t;
  const float* xb = x + (size_t)b * CN * LN + l;
  float acc = 0.f;
#pragma unroll
  for (int c = 0; c < CN; c++) { float v = xb[(size_t)c * LN]; acc = fmaf(v, v, acc); }
  float svm = sqrtf(acc);
  ws[OFF_SVMBUF + (size_t)b * LN + l] = svm;
  const int third = LN / 3;        // 1365
  float vS = svm, vS2 = svm * svm;
  float vS2H  = (l >= LN/2) ? svm : 0.f;
  float vS2H2 = (l >= LN/2) ? svm * svm : 0.f;
  float vPRE  = (l < third) ? svm : 0.f;
  float vPOST = (l >= 2*third) ? svm : 0.f;
  float vMX = svm;
  float vMID = (l >= third && l < 2*third) ? svm : 0.f;
  for (int off = 32; off > 0; off >>= 1) {
    vS += __shfl_down(vS, off); vS2 += __shfl_down(vS2, off);
    vS2H += __shfl_down(vS2H, off); vS2H2 += __shfl_down(vS2H2, off);
    vPRE += __shfl_down(vPRE, off); vPOST += __shfl_down(vPOST, off);
    vMX = fmaxf(vMX, __shfl_down(vMX, off));
    vMID = fmaxf(vMID, __shfl_down(vMID, off));
  }
  __shared__ float red[8][4];
  int w = t >> 6;
  if ((t & 63) == 0) {
    red[0][w] = vS; red[1][w] = vS2; red[2][w] = vMX; red[3][w] = vS2H;
    red[4][w] = vS2H2; red[5][w] = vPRE; red[6][w] = vMID; red[7][w] = vPOST;
  }
  __syncthreads();
  if (t == 0) {
    float S = red[0][0]+red[0][1]+red[0][2]+red[0][3];
    float S2 = red[1][0]+red[1][1]+red[1][2]+red[1][3];
    float MX = fmaxf(fmaxf(red[2][0],red[2][1]),fmaxf(red[2][2],red[2][3]));
    float S2H = red[3][0]+red[3][1]+red[3][2]+red[3][3];
    float S2H2 = red[4][0]+red[4][1]+red[4][2]+red[4][3];
    float PRE = red[5][0]+red[5][1]+red[5][2]+red[5][3];
    float MID = fmaxf(fmaxf(red[6][0],red[6][1]),fmaxf(red[6][2],red[6][3]));
    float POST = red[7][0]+red[7][1]+red[7][2]+red[7][3];
    float* st = ws + OFF_SVMST + b * 16;
    atomicAdd(&st[0], S); atomicAdd(&st[1], S2);
    atomicMax((int*)&st[2], __float_as_int(MX));
    atomicAdd(&st[3], S2H); atomicAdd(&st[4], S2H2);
    atomicAdd(&st[5], PRE);
    atomicMax((int*)&st[6], __float_as_int(MID));
    atomicAdd(&st[7], POST);
  }
}

// ---------------- K3: radix-4 FFT, float2 LDS with skew pad + twiddle table ----------------
#define FP(i) ((i) + ((i) >> 4))
__global__ __launch_bounds__(NTH) void k3_fft(const float* __restrict__ x, float* __restrict__ ws) {
  int blk = blockIdx.x;            // b*32 + cpair
  int b = blk >> 5, cp = blk & 31;
  const float* r0 = x + ((size_t)b * CN + 2 * cp) * LN;
  const float* r1 = r0 + LN;
  __shared__ float2 z[FP(4096)];   // 4352 float2 = 34816 B
  __shared__ float2 tw[1024];      // 8 KB: tw[p] = exp(-i*pi*p/2048)
  __shared__ float red[3][4];
  int t = threadIdx.x;
#pragma unroll
  for (int q = 0; q < 4; q++) {
    int p = q * 256 + t;
    float sv, cv;
    sincospif((float)p * (1.0f / 2048.0f), &sv, &cv);
    tw[p] = make_float2(cv, -sv);
  }
  // load with base-4 digit-reversal
#pragma unroll
  for (int k = 0; k < 4; k++) {
    int n4 = (k * 256 + t) * 4;
    float4 a = *(const float4*)(r0 + n4);
    float4 c = *(const float4*)(r1 + n4);
    float ar[4] = {a.x, a.y, a.z, a.w}, cr[4] = {c.x, c.y, c.z, c.w};
#pragma unroll
    for (int q = 0; q < 4; q++) {
      unsigned n = (unsigned)(n4 + q);
      unsigned br = __brev(n) >> 20;
      unsigned dr = ((br & 0x555u) << 1) | ((br & 0xAAAu) >> 1);
      z[FP(dr)] = make_float2(ar[q], cr[q]);
    }
  }
  __syncthreads();
  // stage 0 (half=1): twiddles are all 1
#pragma unroll
  for (int u = 0; u < 4; u++) {
    int j = u * 256 + t;
    int i0 = 4 * j;
    float2 x0 = z[FP(i0)], x1 = z[FP(i0+1)], x2 = z[FP(i0+2)], x3 = z[FP(i0+3)];
    float ar = x0.x + x2.x, ai = x0.y + x2.y;
    float br_ = x0.x - x2.x, bi = x0.y - x2.y;
    float cr = x1.x + x3.x, ci = x1.y + x3.y;
    float dr_ = x1.x - x3.x, di = x1.y - x3.y;
    z[FP(i0)]   = make_float2(ar + cr, ai + ci);
    z[FP(i0+1)] = make_float2(br_ + di, bi - dr_);
    z[FP(i0+2)] = make_float2(ar - cr, ai - ci);
    z[FP(i0+3)] = make_float2(br_ - di, bi + dr_);
  }
  __syncthreads();
  // stages 1..5
#pragma unroll
  for (int s = 1; s < 6; s++) {
    int half = 1 << (2 * s);
    int shft = 10 - 2 * s;
#pragma unroll
    for (int u = 0; u < 4; u++) {
      int j = u * 256 + t;
      int pos = j & (half - 1);
      int i0 = ((j >> (2 * s)) << (2 * s + 2)) + pos;
      float2 x0 = z[FP(i0)];
      float2 x1 = z[FP(i0 + half)];
      float2 x2 = z[FP(i0 + 2 * half)];
      float2 x3 = z[FP(i0 + 3 * half)];
      float2 w1 = tw[pos << shft];
      float w1r = w1.x, w1i = w1.y;
      float w2r = w1r*w1r - w1i*w1i, w2i = 2.f*w1r*w1i;
      float w3r = w2r*w1r - w2i*w1i, w3i = w2r*w1i + w2i*w1r;
      float t1r = x1.x*w1r - x1.y*w1i, t1i = x1.x*w1i + x1.y*w1r;
      float t2r = x2.x*w2r - x2.y*w2i, t2i = x2.x*w2i + x2.y*w2r;
      float t3r = x3.x*w3r - x3.y*w3i, t3i = x3.x*w3i + x3.y*w3r;
      float ar = x0.x + t2r, ai = x0.y + t2i;
      float br_ = x0.x - t2r, bi = x0.y - t2i;
      float cr = t1r + t3r, ci = t1i + t3i;
      float dr_ = t1r - t3r, di = t1i - t3i;
      z[FP(i0)]            = make_float2(ar + cr, ai + ci);
      z[FP(i0 + half)]     = make_float2(br_ + di, bi - dr_);
      z[FP(i0 + 2*half)]   = make_float2(ar - cr, ai - ci);
      z[FP(i0 + 3*half)]   = make_float2(br_ - di, bi + dr_);
    }
    __syncthreads();
  }
  // power + spectral partial sums (conjugate-symmetry unpack of 2 packed real channels)
  float tot = 0.f, cen = 0.f, hi = 0.f;
  for (int k = t; k <= LN / 2; k += NTH) {
    float p;
    if (k == 0 || k == LN / 2) {
      float2 v = z[FP(k)];
      p = v.x * v.x + v.y * v.y;
    } else {
      float2 zk = z[FP(k)], zn = z[FP(LN - k)];
      float a1 = zk.x + zn.x, a2 = zk.y - zn.y, a3 = zk.y + zn.y, a4 = zk.x - zn.x;
      p = 0.25f * (a1*a1 + a2*a2 + a3*a3 + a4*a4);
    }
    p *= (1.0f / LN);
    tot += p;
    cen += p * ((float)k * (1.0f / (LN / 2)));
    if (k >= 820) hi += p;
  }
  for (int off = 32; off > 0; off >>= 1) {
    tot += __shfl_down(tot, off);
    cen += __shfl_down(cen, off);
    hi  += __shfl_down(hi, off);
  }
  int w = t >> 6;
  if ((t & 63) == 0) { red[0][w] = tot; red[1][w] = cen; red[2][w] = hi; }
  __syncthreads();
  if (t == 0) {
    atomicAdd(&ws[OFF_SPEC + b*3 + 0], red[0][0]+red[0][1]+red[0][2]+red[0][3]);
    atomicAdd(&ws[OFF_SPEC + b*3 + 1], red[1][0]+red[1][1]+red[1][2]+red[1][3]);
    atomicAdd(&ws[OFF_SPEC + b*3 + 2], red[2][0]+red[2][1]+red[2][2]+red[2][3]);
  }
}

// ---------------- K4: threshold counts + gate MLPs + effective conv kernels ----------------
__global__ __launch_bounds__(NTH) void k4_gate(
    const float* __restrict__ dw7, const float* __restrict__ dw15,
    const float* __restrict__ dw31, const float* __restrict__ dw63,
    const float* __restrict__ bn_g, const float* __restrict__ bn_b,
    const float* __restrict__ bn_m, const float* __restrict__ bn_v,
    const float* __restrict__ comp_w1, const float* __restrict__ comp_b1,
    const float* __restrict__ comp_w2, const float* __restrict__ comp_b2,
    const float* __restrict__ pn_g, const float* __restrict__ pn_b,
    const float* __restrict__ pn_m, const float* __restrict__ pn_v,
    const float* __restrict__ pe_w1, const float* __restrict__ pe_b1,
    const float* __restrict__ pe_w2, const float* __restrict__ pe_b2,
    const float* __restrict__ pg_w, const float* __restrict__ pg_b,
    const float* __restrict__ temperature,
    float* __restrict__ ws)
{
  int b = blockIdx.x, t = threadIdx.x;
  __shared__ float xm[64], h[64], pf[12], pe1v[32], pe2v[32], lgts[4], wts[4];
  __shared__ int ri[3][4], cnts[3];
  const float* st = ws + OFF_SVMST + b * 16;
  float S = st[0], S2 = st[1];
  float mean = S * (1.f / LN);
  float var = (S2 - S * S * (1.f / LN)) * (1.f / (LN - 1));
  var = fmaxf(var, 0.f);
  float stde = sqrtf(var) + 1e-6f;
  float thr2 = mean + 2.f * stde, thr3 = mean + 3.f * stde, thrf = mean - stde;
  const float* svm = ws + OFF_SVMBUF + (size_t)b * LN;
  int c2 = 0, c3 = 0, cf = 0;
  for (int l = t; l < LN; l += NTH) {
    float v = svm[l];
    c2 += (v > thr2); c3 += (v > thr3); cf += (v < thrf);
  }
  for (int off = 32; off > 0; off >>= 1) {
    c2 += __shfl_down(c2, off); c3 += __shfl_down(c3, off); cf += __shfl_down(cf, off);
  }
  int w = t >> 6;
  if ((t & 63) == 0) { ri[0][w] = c2; ri[1][w] = c3; ri[2][w] = cf; }
  float j = 0.f, jr = 0.f, zz = 0.f;
  if (t < 64) {
    xm[t] = ws[OFF_CHAN_SUM + b * 64 + t] * (1.0f / LN);
    j  = ws[OFF_CHAN_JERK + b * 64 + t];
    jr = ws[OFF_CHAN_JRATE + b * 64 + t];
    zz = ws[OFF_CHAN_ZCR + b * 64 + t];
    for (int off = 32; off > 0; off >>= 1) {
      j += __shfl_down(j, off); jr += __shfl_down(jr, off); zz += __shfl_down(zz, off);
    }
  }
  __syncthreads();
  if (t == 0) {
    cnts[0] = ri[0][0]+ri[0][1]+ri[0][2]+ri[0][3];
    cnts[1] = ri[1][0]+ri[1][1]+ri[1][2]+ri[1][3];
    cnts[2] = ri[2][0]+ri[2][1]+ri[2][2]+ri[2][3];
    float tot = ws[OFF_SPEC + b*3 + 0];
    float cenv = ws[OFF_SPEC + b*3 + 1];
    float hiv = ws[OFF_SPEC + b*3 + 2];
    const int third = LN / 3;
    float S2H = st[3], S2H2 = st[4];
    float n2 = (float)(LN / 2);
    float var2 = (S2H2 - S2H * S2H / n2) / (n2 - 1.f);
    var2 = fmaxf(var2, 0.f);
    float post_still = tanhf(1.f / (sqrtf(var2) + 1e-6f));
    float pre_mean = st[5] / (float)third;
    float post_mean = st[7] / (float)(LN - 2 * third);
    float pk = st[6];
    float fp = fmaxf(pk - pre_mean, 0.f) + fmaxf(pk - post_mean, 0.f);
    fp = fp / (fabsf(pk) + 1e-6f);
    pf[0] = st[2];                     // svm_max
    pf[1] = mean;
    pf[2] = j * (1.f / 64);
    pf[3] = jr * (1.f / 64);
    pf[4] = (zz * (1.f / 64)) * (1.f / LN);
    pf[5] = (float)cnts[0] / LN;
    pf[6] = (float)cnts[1] / LN;
    pf[7] = post_still;
    pf[8] = (float)cnts[2] / LN;
    pf[9] = cenv / (tot + 1e-6f);
    pf[10] = hiv / (tot + 1e-6f);
    pf[11] = fp;
  }
  __syncthreads();
  if (t < 12) pf[t] = (pf[t] - pn_m[t]) * rsqrtf(pn_v[t] + 1e-5f) * pn_g[t] + pn_b[t];
  __syncthreads();
  if (t < 64) {
    float hv = comp_b1[t];
    for (int i = 0; i < 64; i++) hv = fmaf(xm[i], comp_w1[i * 64 + t], hv);
    h[t] = fmaxf(hv, 0.f);
  }
  if (t < 32) {
    float v = pe_b1[t];
    for (int i = 0; i < 12; i++) v = fmaf(pf[i], pe_w1[i * 32 + t], v);
    pe1v[t] = fmaxf(v, 0.f);
  }
  __syncthreads();
  if (t < 32) {
    float v = pe_b2[t];
    for (int i = 0; i < 32; i++) v = fmaf(pe1v[i], pe_w2[i * 32 + t], v);
    pe2v[t] = fmaxf(v, 0.f);
  }
  __syncthreads();
  if (t < 4) {
    float v = comp_b2[t];
    for (int i = 0; i < 64; i++) v = fmaf(h[i], comp_w2[i * 4 + t], v);
    float g = pg_b[t];
    for (int i = 0; i < 32; i++) g = fmaf(pe2v[i], pg_w[i * 4 + t], g);
    g = 1.f / (1.f + expf(-g));
    float temp = fmaxf(temperature[0], 0.1f);
    lgts[t] = v * g / temp;
  }
  __syncthreads();
  if (t < 4) {
    float m = fmaxf(fmaxf(lgts[0], lgts[1]), fmaxf(lgts[2], lgts[3]));
    float den = expf(lgts[0]-m) + expf(lgts[1]-m) + expf(lgts[2]-m) + expf(lgts[3]-m);
    wts[t] = expf(lgts[t] - m) / den;
  }
  __syncthreads();
  if (t < 64) {
    int c = t;
    float w0 = wts[0], w1 = wts[1], w2 = wts[2], w3 = wts[3];
    float sc0 = bn_g[0*64+c] * rsqrtf(bn_v[0*64+c] + 1e-5f);
    float sc1 = bn_g[1*64+c] * rsqrtf(bn_v[1*64+c] + 1e-5f);
    float sc2 = bn_g[2*64+c] * rsqrtf(bn_v[2*64+c] + 1e-5f);
    float sc3 = bn_g[3*64+c] * rsqrtf(bn_v[3*64+c] + 1e-5f);
    float o0 = bn_b[0*64+c] - bn_m[0*64+c] * sc0;
    float o1 = bn_b[1*64+c] - bn_m[1*64+c] * sc1;
    float o2 = bn_b[2*64+c] - bn_m[2*64+c] * sc2;
    float o3 = bn_b[3*64+c] - bn_m[3*64+c] * sc3;
    ws[OFF_EFF_B + b * 64 + c] = w0*o0 + w1*o1 + w2*o2 + w3*o3;
    float a0 = w0*sc0, a1 = w1*sc1, a2 = w2*sc2, a3 = w3*sc3;
    float* eff = ws + OFF_EFF_W + (size_t)(b * 64 + c) * 64;
    for (int tau = 0; tau < 64; tau++) {
      float v = 0.f;
      if (tau < 63) {
        v = a3 * dw63[c * 63 + tau];
        int i7 = tau - 28;  if (i7 >= 0 && i7 < 7)   v = fmaf(a0, dw7[c * 7 + i7], v);
        int i15 = tau - 24; if (i15 >= 0 && i15 < 15) v = fmaf(a1, dw15[c * 15 + i15], v);
        int i31 = tau - 16; if (i31 >= 0 && i31 < 31) v = fmaf(a2, dw31[c * 31 + i31], v);
      }
      eff[tau] = v;
    }
  }
}

// ---------------- K5: 63-tap conv, window direct from global into VGPRs ----------------
__global__ __launch_bounds__(NTH) void k5_conv(const float* __restrict__ x,
                                               float* __restrict__ ws,
                                               float* __restrict__ mixed_out) {
  int bc = blockIdx.x;
  int b = bc >> 6;
  int t = threadIdx.x;
  __shared__ float wt[64];
  __shared__ float biasS;
  __shared__ double rda[2][4];
  if (t < 64) wt[t] = ws[OFF_EFF_W + (size_t)bc * 64 + t];
  if (t == 0) biasS = ws[OFF_EFF_B + bc];
  const float* row = x + (size_t)bc * LN;
  int l0 = t * 16;
  int g0 = l0 - 32;
  float xw[80];
  if (t >= 2 && t <= 253) {
    const float4* p = (const float4*)(row + g0);   // 64B aligned (g0 = 16t-32)
#pragma unroll
    for (int q = 0; q < 20; q++) {
      float4 v = p[q];
      xw[4*q] = v.x; xw[4*q+1] = v.y; xw[4*q+2] = v.z; xw[4*q+3] = v.w;
    }
  } else {
#pragma unroll
    for (int i = 0; i < 80; i++) {
      int idx = g0 + i;
      xw[i] = (idx >= 0 && idx < LN) ? row[idx] : 0.f;
    }
  }
  __syncthreads();
  float bias = biasS;
  float acc[16];
#pragma unroll
  for (int jj = 0; jj < 16; jj++) acc[jj] = bias;
#pragma unroll
  for (int tau = 0; tau < 63; tau++) {
    float w = wt[tau];
#pragma unroll
    for (int jj = 0; jj < 16; jj++) acc[jj] = fmaf(w, xw[jj + tau + 1], acc[jj]);
  }
  double ls = 0, ls2 = 0;
#pragma unroll
  for (int jj = 0; jj < 16; jj++) { float v = acc[jj]; ls += v; ls2 += (double)v * (double)v; }
  for (int off = 32; off > 0; off >>= 1) {
    ls += __shfl_down(ls, off);
    ls2 += __shfl_down(ls2, off);
  }
  int w = t >> 6;
  if ((t & 63) == 0) { rda[0][w] = ls; rda[1][w] = ls2; }
  __syncthreads();
  if (t == 0) {
    double* gacc = (double*)(ws + OFF_GN);
    atomicAdd(&gacc[b * 2 + 0], rda[0][0]+rda[0][1]+rda[0][2]+rda[0][3]);
    atomicAdd(&gacc[b * 2 + 1], rda[1][0]+rda[1][1]+rda[1][2]+rda[1][3]);
  }
  float* dst = mixed_out + (size_t)bc * LN + l0;
#pragma unroll
  for (int q = 0; q < 4; q++) {
    float4 v; v.x = acc[4*q]; v.y = acc[4*q+1]; v.z = acc[4*q+2]; v.w = acc[4*q+3];
    *(float4*)(dst + 4 * q) = v;
  }
}

// ---------------- K6: GN + GELU + proj + residual ----------------
__global__ __launch_bounds__(NTH) void k6_final(const float* __restrict__ x,
    const float* __restrict__ proj_w, const float* __restrict__ proj_b,
    const float* __restrict__ gn_g, const float* __restrict__ gn_b,
    const float* __restrict__ res_scale,
    const float* __restrict__ ws, float* out) {
  int blk = blockIdx.x;
  int b = blk >> 5;
  int l0 = (blk & 31) * 128;
  __shared__ float actS[64 * 128];
  __shared__ float Wt[64 * 64];
  const double* gacc = (const double*)(ws + OFF_GN);
  double s1 = gacc[b * 2 + 0], s2d = gacc[b * 2 + 1];
  const double NN = 64.0 * 4096.0;
  double mud = s1 / NN;
  float mu = (float)mud;
  float var = (float)(s2d / NN - mud * mud);
  float rstd = rsqrtf(var + 1e-5f);
  for (int i = threadIdx.x; i < 4096; i += NTH) {
    int o = i & 63, c = i >> 6;
    Wt[c * 64 + o] = proj_w[o * 64 + c];
  }
  const float* mx = out + (size_t)b * CN * LN;
  for (int i = threadIdx.x; i < 8192; i += NTH) {
    int c = i >> 7, l = i & 127;
    float v = mx[(size_t)c * LN + l0 + l];
    float g = (v - mu) * rstd * gn_g[c] + gn_b[c];
    float a = 0.5f * g * (1.f + erff(g * 0.70710678118654752f));
    actS[c * 128 + l] = a;
  }
  __syncthreads();
  int lg = threadIdx.x & 31;
  int og = (threadIdx.x >> 5) * 8;
  float4 acc4[8];
#pragma unroll
  for (int q = 0; q < 8; q++) { acc4[q].x = 0.f; acc4[q].y = 0.f; acc4[q].z = 0.f; acc4[q].w = 0.f; }
  for (int c = 0; c < 64; c++) {
    float4 a = *(const float4*)&actS[c * 128 + lg * 4];
    float4 wlo = *(const float4*)&Wt[c * 64 + og];
    float4 whi = *(const float4*)&Wt[c * 64 + og + 4];
    float wv[8] = { wlo.x, wlo.y, wlo.z, wlo.w, whi.x, whi.y, whi.z, whi.w };
#pragma unroll
    for (int q = 0; q < 8; q++) {
      acc4[q].x = fmaf(wv[q], a.x, acc4[q].x);
      acc4[q].y = fmaf(wv[q], a.y, acc4[q].y);
      acc4[q].z = fmaf(wv[q], a.z, acc4[q].z);
      acc4[q].w = fmaf(wv[q], a.w, acc4[q].w);
    }
  }
  float rsv = res_scale[0];
  const float* xb = x + (size_t)b * CN * LN;
  float* ob = out + (size_t)b * CN * LN;
#pragma unroll
  for (int q = 0; q < 8; q++) {
    int o = og + q;
    float pb = proj_b[o];
    size_t base = (size_t)o * LN + l0 + lg * 4;
    float4 xv = *(const float4*)&xb[base];
    float4 r;
    r.x = xv.x + rsv * (acc4[q].x + pb);
    r.y = xv.y + rsv * (acc4[q].y + pb);
    r.z = xv.z + rsv * (acc4[q].z + pb);
    r.w = xv.w + rsv * (acc4[q].w + pb);
    *(float4*)&ob[base] = r;
  }
}

extern "C" void kernel_launch(void* const* d_in, const int* in_sizes, int n_in,
                              void* d_out, int out_size, void* d_ws, size_t ws_size,
                              hipStream_t stream) {
  const float* x        = (const float*)d_in[0];
  const float* dw7      = (const float*)d_in[1];
  const float* dw15     = (const float*)d_in[2];
  const float* dw31     = (const float*)d_in[3];
  const float* dw63     = (const float*)d_in[4];
  const float* bn_g     = (const float*)d_in[5];
  const float* bn_b     = (const float*)d_in[6];
  const float* bn_m     = (const float*)d_in[7];
  const float* bn_v     = (const float*)d_in[8];
  const float* comp_w1  = (const float*)d_in[9];
  const float* comp_b1  = (const float*)d_in[10];
  const float* comp_w2  = (const float*)d_in[11];
  const float* comp_b2  = (const float*)d_in[12];
  const float* pn_g     = (const float*)d_in[13];
  const float* pn_b     = (const float*)d_in[14];
  const float* pn_m     = (const float*)d_in[15];
  const float* pn_v     = (const float*)d_in[16];
  const float* pe_w1    = (const float*)d_in[17];
  const float* pe_b1    = (const float*)d_in[18];
  const float* pe_w2    = (const float*)d_in[19];
  const float* pe_b2    = (const float*)d_in[20];
  const float* pg_w     = (const float*)d_in[21];
  const float* pg_b     = (const float*)d_in[22];
  const float* temperature = (const float*)d_in[23];
  const float* gn_g     = (const float*)d_in[24];
  const float* gn_b     = (const float*)d_in[25];
  const float* proj_w   = (const float*)d_in[26];
  const float* proj_b   = (const float*)d_in[27];
  const float* res_scale= (const float*)d_in[28];
  float* ws = (float*)d_ws;
  float* out = (float*)d_out;

  hipLaunchKernelGGL(k0_zero, dim3(1), dim3(512), 0, stream, ws);
  hipLaunchKernelGGL(k1_chan, dim3(BQ * CN), dim3(NTH), 0, stream, x, ws);
  hipLaunchKernelGGL(kA_svm, dim3(BQ * 16), dim3(NTH), 0, stream, x, ws);
  hipLaunchKernelGGL(k3_fft, dim3(BQ * 32), dim3(NTH), 0, stream, x, ws);
  hipLaunchKernelGGL(k4_gate, dim3(BQ), dim3(NTH), 0, stream,
                     dw7, dw15, dw31, dw63, bn_g, bn_b, bn_m, bn_v,
                     comp_w1, comp_b1, comp_w2, comp_b2,
                     pn_g, pn_b, pn_m, pn_v, pe_w1, pe_b1, pe_w2, pe_b2,
                     pg_w, pg_b, temperature, ws);
  hipLaunchKernelGGL(k5_conv, dim3(BQ * CN), dim3(NTH), 0, stream, x, ws, out);
  hipLaunchKernelGGL(k6_final, dim3(BQ * 32), dim3(NTH), 0, stream,
                     x, proj_w, proj_b, gn_g, gn_b, res_scale, ws, out);
}

// Round 4
// 280.199 us; speedup vs baseline: 1.0426x; 1.0426x over previous
//
#include <hip/hip_runtime.h>
#include <math.h>

#define LN 4096
#define CN 64
#define BQ 32
#define NTH 256

// ws offsets (floats)
#define OFF_CHAN_SUM   0        // 2048
#define OFF_CHAN_JERK  2048     // 2048
#define OFF_CHAN_JRATE 4096     // 2048
#define OFF_CHAN_ZCR   6144     // 2048
#define OFF_SVMST      8192     // 32*16 per-b stat accumulators
#define OFF_SPEC       8704     // 32*3
#define OFF_EFF_B      8800     // 2048
#define OFF_GN         10848    // 64 doubles = 128 floats (byte off 43392 %8==0)
#define OFF_EFF_W      10976    // 2048*64
#define OFF_SVMBUF     142048   // 32*4096

// ---------------- K0: zero atomic accumulators ----------------
__global__ void k0_zero(float* __restrict__ ws) {
  int t = threadIdx.x;
  if (t < 512) ws[OFF_SVMST + t] = 0.f;
  if (t < 96)  ws[OFF_SPEC + t] = 0.f;
  if (t < 128) ws[OFF_GN + t] = 0.f;
}

// ---------------- K1: per-(b,c) scans, register chunks + shuffle reduce ----------------
__global__ __launch_bounds__(NTH) void k1_chan(const float* __restrict__ x, float* __restrict__ ws) {
  int bc = blockIdx.x;
  const float* row = x + (size_t)bc * LN;
  int t = threadIdx.x;
  int l0 = t * 16;
  float rd[18];
  const float4* r4 = (const float4*)(row + l0);
#pragma unroll
  for (int q = 0; q < 4; q++) {
    float4 v = r4[q];
    rd[4*q] = v.x; rd[4*q+1] = v.y; rd[4*q+2] = v.z; rd[4*q+3] = v.w;
  }
  if (t < 255) { rd[16] = row[l0 + 16]; rd[17] = row[l0 + 17]; }
  else { rd[16] = 0.f; rd[17] = 0.f; }
  float lsum = 0.f, jm = 0.f, jrm = 0.f; int zc = 0;
#pragma unroll
  for (int i = 0; i < 16; i++) {
    float a = rd[i], b2 = rd[i+1];
    lsum += a;
    int l = l0 + i;
    if (l < LN - 1) {
      jm = fmaxf(jm, fabsf(b2 - a));
      zc += (a * b2 < 0.f);
      if (l < LN - 2) jrm = fmaxf(jrm, fabsf(rd[i+2] - 2.f*b2 + a));
    }
  }
  for (int off = 32; off > 0; off >>= 1) {
    lsum += __shfl_down(lsum, off);
    jm = fmaxf(jm, __shfl_down(jm, off));
    jrm = fmaxf(jrm, __shfl_down(jrm, off));
    zc += __shfl_down(zc, off);
  }
  __shared__ float s1[4], s2_[4], s3[4]; __shared__ int s4[4];
  int w = t >> 6;
  if ((t & 63) == 0) { s1[w] = lsum; s2_[w] = jm; s3[w] = jrm; s4[w] = zc; }
  __syncthreads();
  if (t == 0) {
    float S = 0, J = 0, JR = 0; int Z = 0;
    for (int i = 0; i < 4; i++) { S += s1[i]; J = fmaxf(J, s2_[i]); JR = fmaxf(JR, s3[i]); Z += s4[i]; }
    ws[OFF_CHAN_SUM + bc]   = S;
    ws[OFF_CHAN_JERK + bc]  = J * 50.f;
    ws[OFF_CHAN_JRATE + bc] = JR * 2500.f;
    ws[OFF_CHAN_ZCR + bc]   = (float)Z;
  }
}

// ---------------- KA: svm + partial stats (512 blocks) ----------------
__global__ __launch_bounds__(NTH) void kA_svm(const float* __restrict__ x, float* __restrict__ ws) {
  int blk = blockIdx.x;            // b*16 + lt
  int b = blk >> 4, lt = blk & 15;
  int t = threadIdx.x;
  int l = lt * 256 + t;
  const float* xb = x + (size_t)b * CN * LN + l;
  float acc = 0.f;
#pragma unroll
  for (int c = 0; c < CN; c++) { float v = xb[(size_t)c * LN]; acc = fmaf(v, v, acc); }
  float svm = sqrtf(acc);
  ws[OFF_SVMBUF + (size_t)b * LN + l] = svm;
  const int third = LN / 3;        // 1365
  float vS = svm, vS2 = svm * svm;
  float vS2H  = (l >= LN/2) ? svm : 0.f;
  float vS2H2 = (l >= LN/2) ? svm * svm : 0.f;
  float vPRE  = (l < third) ? svm : 0.f;
  float vPOST = (l >= 2*third) ? svm : 0.f;
  float vMX = svm;
  float vMID = (l >= third && l < 2*third) ? svm : 0.f;
  for (int off = 32; off > 0; off >>= 1) {
    vS += __shfl_down(vS, off); vS2 += __shfl_down(vS2, off);
    vS2H += __shfl_down(vS2H, off); vS2H2 += __shfl_down(vS2H2, off);
    vPRE += __shfl_down(vPRE, off); vPOST += __shfl_down(vPOST, off);
    vMX = fmaxf(vMX, __shfl_down(vMX, off));
    vMID = fmaxf(vMID, __shfl_down(vMID, off));
  }
  __shared__ float red[8][4];
  int w = t >> 6;
  if ((t & 63) == 0) {
    red[0][w] = vS; red[1][w] = vS2; red[2][w] = vMX; red[3][w] = vS2H;
    red[4][w] = vS2H2; red[5][w] = vPRE; red[6][w] = vMID; red[7][w] = vPOST;
  }
  __syncthreads();
  if (t == 0) {
    float S = red[0][0]+red[0][1]+red[0][2]+red[0][3];
    float S2 = red[1][0]+red[1][1]+red[1][2]+red[1][3];
    float MX = fmaxf(fmaxf(red[2][0],red[2][1]),fmaxf(red[2][2],red[2][3]));
    float S2H = red[3][0]+red[3][1]+red[3][2]+red[3][3];
    float S2H2 = red[4][0]+red[4][1]+red[4][2]+red[4][3];
    float PRE = red[5][0]+red[5][1]+red[5][2]+red[5][3];
    float MID = fmaxf(fmaxf(red[6][0],red[6][1]),fmaxf(red[6][2],red[6][3]));
    float POST = red[7][0]+red[7][1]+red[7][2]+red[7][3];
    float* st = ws + OFF_SVMST + b * 16;
    atomicAdd(&st[0], S); atomicAdd(&st[1], S2);
    atomicMax((int*)&st[2], __float_as_int(MX));
    atomicAdd(&st[3], S2H); atomicAdd(&st[4], S2H2);
    atomicAdd(&st[5], PRE);
    atomicMax((int*)&st[6], __float_as_int(MID));
    atomicAdd(&st[7], POST);
  }
}

// ---------------- K3: radix-4 FFT, float2 LDS with skew pad (inline sincospif) ----------------
#define FP(i) ((i) + ((i) >> 4))
__global__ __launch_bounds__(NTH) void k3_fft(const float* __restrict__ x, float* __restrict__ ws) {
  int blk = blockIdx.x;            // b*32 + cpair
  int b = blk >> 5, cp = blk & 31;
  const float* r0 = x + ((size_t)b * CN + 2 * cp) * LN;
  const float* r1 = r0 + LN;
  __shared__ float2 z[FP(4096)];   // 4352 float2 = 34816 B
  __shared__ float red[3][4];
  int t = threadIdx.x;
  // load with base-4 digit-reversal
#pragma unroll
  for (int k = 0; k < 4; k++) {
    int n4 = (k * 256 + t) * 4;
    float4 a = *(const float4*)(r0 + n4);
    float4 c = *(const float4*)(r1 + n4);
    float ar[4] = {a.x, a.y, a.z, a.w}, cr[4] = {c.x, c.y, c.z, c.w};
#pragma unroll
    for (int q = 0; q < 4; q++) {
      unsigned n = (unsigned)(n4 + q);
      unsigned br = __brev(n) >> 20;
      unsigned dr = ((br & 0x555u) << 1) | ((br & 0xAAAu) >> 1);
      z[FP(dr)] = make_float2(ar[q], cr[q]);
    }
  }
  __syncthreads();
  // stage 0 (half=1): twiddles are all 1
#pragma unroll
  for (int u = 0; u < 4; u++) {
    int j = u * 256 + t;
    int i0 = 4 * j;
    float2 x0 = z[FP(i0)], x1 = z[FP(i0+1)], x2 = z[FP(i0+2)], x3 = z[FP(i0+3)];
    float ar = x0.x + x2.x, ai = x0.y + x2.y;
    float br_ = x0.x - x2.x, bi = x0.y - x2.y;
    float cr = x1.x + x3.x, ci = x1.y + x3.y;
    float dr_ = x1.x - x3.x, di = x1.y - x3.y;
    z[FP(i0)]   = make_float2(ar + cr, ai + ci);
    z[FP(i0+1)] = make_float2(br_ + di, bi - dr_);
    z[FP(i0+2)] = make_float2(ar - cr, ai - ci);
    z[FP(i0+3)] = make_float2(br_ - di, bi + dr_);
  }
  __syncthreads();
  // stages 1..5
#pragma unroll
  for (int s = 1; s < 6; s++) {
    int half = 1 << (2 * s);
    float angscale = 1.0f / (float)(2 * half);
#pragma unroll
    for (int u = 0; u < 4; u++) {
      int j = u * 256 + t;
      int pos = j & (half - 1);
      int i0 = ((j >> (2 * s)) << (2 * s + 2)) + pos;
      float2 x0 = z[FP(i0)];
      float2 x1 = z[FP(i0 + half)];
      float2 x2 = z[FP(i0 + 2 * half)];
      float2 x3 = z[FP(i0 + 3 * half)];
      float sv, cv;
      sincospif((float)pos * angscale, &sv, &cv);
      float w1r = cv, w1i = -sv;
      float w2r = w1r*w1r - w1i*w1i, w2i = 2.f*w1r*w1i;
      float w3r = w2r*w1r - w2i*w1i, w3i = w2r*w1i + w2i*w1r;
      float t1r = x1.x*w1r - x1.y*w1i, t1i = x1.x*w1i + x1.y*w1r;
      float t2r = x2.x*w2r - x2.y*w2i, t2i = x2.x*w2i + x2.y*w2r;
      float t3r = x3.x*w3r - x3.y*w3i, t3i = x3.x*w3i + x3.y*w3r;
      float ar = x0.x + t2r, ai = x0.y + t2i;
      float br_ = x0.x - t2r, bi = x0.y - t2i;
      float cr = t1r + t3r, ci = t1i + t3i;
      float dr_ = t1r - t3r, di = t1i - t3i;
      z[FP(i0)]            = make_float2(ar + cr, ai + ci);
      z[FP(i0 + half)]     = make_float2(br_ + di, bi - dr_);
      z[FP(i0 + 2*half)]   = make_float2(ar - cr, ai - ci);
      z[FP(i0 + 3*half)]   = make_float2(br_ - di, bi + dr_);
    }
    __syncthreads();
  }
  // power + spectral partial sums (conjugate-symmetry unpack of 2 packed real channels)
  float tot = 0.f, cen = 0.f, hi = 0.f;
  for (int k = t; k <= LN / 2; k += NTH) {
    float p;
    if (k == 0 || k == LN / 2) {
      float2 v = z[FP(k)];
      p = v.x * v.x + v.y * v.y;
    } else {
      float2 zk = z[FP(k)], zn = z[FP(LN - k)];
      float a1 = zk.x + zn.x, a2 = zk.y - zn.y, a3 = zk.y + zn.y, a4 = zk.x - zn.x;
      p = 0.25f * (a1*a1 + a2*a2 + a3*a3 + a4*a4);
    }
    p *= (1.0f / LN);
    tot += p;
    cen += p * ((float)k * (1.0f / (LN / 2)));
    if (k >= 820) hi += p;
  }
  for (int off = 32; off > 0; off >>= 1) {
    tot += __shfl_down(tot, off);
    cen += __shfl_down(cen, off);
    hi  += __shfl_down(hi, off);
  }
  int w = t >> 6;
  if ((t & 63) == 0) { red[0][w] = tot; red[1][w] = cen; red[2][w] = hi; }
  __syncthreads();
  if (t == 0) {
    atomicAdd(&ws[OFF_SPEC + b*3 + 0], red[0][0]+red[0][1]+red[0][2]+red[0][3]);
    atomicAdd(&ws[OFF_SPEC + b*3 + 1], red[1][0]+red[1][1]+red[1][2]+red[1][3]);
    atomicAdd(&ws[OFF_SPEC + b*3 + 2], red[2][0]+red[2][1]+red[2][2]+red[2][3]);
  }
}

// ---------------- K4: threshold counts + gate MLPs + effective conv kernels ----------------
__global__ __launch_bounds__(NTH) void k4_gate(
    const float* __restrict__ dw7, const float* __restrict__ dw15,
    const float* __restrict__ dw31, const float* __restrict__ dw63,
    const float* __restrict__ bn_g, const float* __restrict__ bn_b,
    const float* __restrict__ bn_m, const float* __restrict__ bn_v,
    const float* __restrict__ comp_w1, const float* __restrict__ comp_b1,
    const float* __restrict__ comp_w2, const float* __restrict__ comp_b2,
    const float* __restrict__ pn_g, const float* __restrict__ pn_b,
    const float* __restrict__ pn_m, const float* __restrict__ pn_v,
    const float* __restrict__ pe_w1, const float* __restrict__ pe_b1,
    const float* __restrict__ pe_w2, const float* __restrict__ pe_b2,
    const float* __restrict__ pg_w, const float* __restrict__ pg_b,
    const float* __restrict__ temperature,
    float* __restrict__ ws)
{
  int b = blockIdx.x, t = threadIdx.x;
  __shared__ float xm[64], h[64], pf[12], pe1v[32], pe2v[32], lgts[4], wts[4];
  __shared__ int ri[3][4], cnts[3];
  const float* st = ws + OFF_SVMST + b * 16;
  float S = st[0], S2 = st[1];
  float mean = S * (1.f / LN);
  float var = (S2 - S * S * (1.f / LN)) * (1.f / (LN - 1));
  var = fmaxf(var, 0.f);
  float stde = sqrtf(var) + 1e-6f;
  float thr2 = mean + 2.f * stde, thr3 = mean + 3.f * stde, thrf = mean - stde;
  const float* svm = ws + OFF_SVMBUF + (size_t)b * LN;
  int c2 = 0, c3 = 0, cf = 0;
  for (int l = t; l < LN; l += NTH) {
    float v = svm[l];
    c2 += (v > thr2); c3 += (v > thr3); cf += (v < thrf);
  }
  for (int off = 32; off > 0; off >>= 1) {
    c2 += __shfl_down(c2, off); c3 += __shfl_down(c3, off); cf += __shfl_down(cf, off);
  }
  int w = t >> 6;
  if ((t & 63) == 0) { ri[0][w] = c2; ri[1][w] = c3; ri[2][w] = cf; }
  float j = 0.f, jr = 0.f, zz = 0.f;
  if (t < 64) {
    xm[t] = ws[OFF_CHAN_SUM + b * 64 + t] * (1.0f / LN);
    j  = ws[OFF_CHAN_JERK + b * 64 + t];
    jr = ws[OFF_CHAN_JRATE + b * 64 + t];
    zz = ws[OFF_CHAN_ZCR + b * 64 + t];
    for (int off = 32; off > 0; off >>= 1) {
      j += __shfl_down(j, off); jr += __shfl_down(jr, off); zz += __shfl_down(zz, off);
    }
  }
  __syncthreads();
  if (t == 0) {
    cnts[0] = ri[0][0]+ri[0][1]+ri[0][2]+ri[0][3];
    cnts[1] = ri[1][0]+ri[1][1]+ri[1][2]+ri[1][3];
    cnts[2] = ri[2][0]+ri[2][1]+ri[2][2]+ri[2][3];
    float tot = ws[OFF_SPEC + b*3 + 0];
    float cenv = ws[OFF_SPEC + b*3 + 1];
    float hiv = ws[OFF_SPEC + b*3 + 2];
    const int third = LN / 3;
    float S2H = st[3], S2H2 = st[4];
    float n2 = (float)(LN / 2);
    float var2 = (S2H2 - S2H * S2H / n2) / (n2 - 1.f);
    var2 = fmaxf(var2, 0.f);
    float post_still = tanhf(1.f / (sqrtf(var2) + 1e-6f));
    float pre_mean = st[5] / (float)third;
    float post_mean = st[7] / (float)(LN - 2 * third);
    float pk = st[6];
    float fp = fmaxf(pk - pre_mean, 0.f) + fmaxf(pk - post_mean, 0.f);
    fp = fp / (fabsf(pk) + 1e-6f);
    pf[0] = st[2];                     // svm_max
    pf[1] = mean;
    pf[2] = j * (1.f / 64);
    pf[3] = jr * (1.f / 64);
    pf[4] = (zz * (1.f / 64)) * (1.f / LN);
    pf[5] = (float)cnts[0] / LN;
    pf[6] = (float)cnts[1] / LN;
    pf[7] = post_still;
    pf[8] = (float)cnts[2] / LN;
    pf[9] = cenv / (tot + 1e-6f);
    pf[10] = hiv / (tot + 1e-6f);
    pf[11] = fp;
  }
  __syncthreads();
  if (t < 12) pf[t] = (pf[t] - pn_m[t]) * rsqrtf(pn_v[t] + 1e-5f) * pn_g[t] + pn_b[t];
  __syncthreads();
  if (t < 64) {
    float hv = comp_b1[t];
    for (int i = 0; i < 64; i++) hv = fmaf(xm[i], comp_w1[i * 64 + t], hv);
    h[t] = fmaxf(hv, 0.f);
  }
  if (t < 32) {
    float v = pe_b1[t];
    for (int i = 0; i < 12; i++) v = fmaf(pf[i], pe_w1[i * 32 + t], v);
    pe1v[t] = fmaxf(v, 0.f);
  }
  __syncthreads();
  if (t < 32) {
    float v = pe_b2[t];
    for (int i = 0; i < 32; i++) v = fmaf(pe1v[i], pe_w2[i * 32 + t], v);
    pe2v[t] = fmaxf(v, 0.f);
  }
  __syncthreads();
  if (t < 4) {
    float v = comp_b2[t];
    for (int i = 0; i < 64; i++) v = fmaf(h[i], comp_w2[i * 4 + t], v);
    float g = pg_b[t];
    for (int i = 0; i < 32; i++) g = fmaf(pe2v[i], pg_w[i * 4 + t], g);
    g = 1.f / (1.f + expf(-g));
    float temp = fmaxf(temperature[0], 0.1f);
    lgts[t] = v * g / temp;
  }
  __syncthreads();
  if (t < 4) {
    float m = fmaxf(fmaxf(lgts[0], lgts[1]), fmaxf(lgts[2], lgts[3]));
    float den = expf(lgts[0]-m) + expf(lgts[1]-m) + expf(lgts[2]-m) + expf(lgts[3]-m);
    wts[t] = expf(lgts[t] - m) / den;
  }
  __syncthreads();
  if (t < 64) {
    int c = t;
    float w0 = wts[0], w1 = wts[1], w2 = wts[2], w3 = wts[3];
    float sc0 = bn_g[0*64+c] * rsqrtf(bn_v[0*64+c] + 1e-5f);
    float sc1 = bn_g[1*64+c] * rsqrtf(bn_v[1*64+c] + 1e-5f);
    float sc2 = bn_g[2*64+c] * rsqrtf(bn_v[2*64+c] + 1e-5f);
    float sc3 = bn_g[3*64+c] * rsqrtf(bn_v[3*64+c] + 1e-5f);
    float o0 = bn_b[0*64+c] - bn_m[0*64+c] * sc0;
    float o1 = bn_b[1*64+c] - bn_m[1*64+c] * sc1;
    float o2 = bn_b[2*64+c] - bn_m[2*64+c] * sc2;
    float o3 = bn_b[3*64+c] - bn_m[3*64+c] * sc3;
    ws[OFF_EFF_B + b * 64 + c] = w0*o0 + w1*o1 + w2*o2 + w3*o3;
    float a0 = w0*sc0, a1 = w1*sc1, a2 = w2*sc2, a3 = w3*sc3;
    float* eff = ws + OFF_EFF_W + (size_t)(b * 64 + c) * 64;
    for (int tau = 0; tau < 64; tau++) {
      float v = 0.f;
      if (tau < 63) {
        v = a3 * dw63[c * 63 + tau];
        int i7 = tau - 28;  if (i7 >= 0 && i7 < 7)   v = fmaf(a0, dw7[c * 7 + i7], v);
        int i15 = tau - 24; if (i15 >= 0 && i15 < 15) v = fmaf(a1, dw15[c * 15 + i15], v);
        int i31 = tau - 16; if (i31 >= 0 && i31 < 31) v = fmaf(a2, dw31[c * 31 + i31], v);
      }
      eff[tau] = v;
    }
  }
}

// ---------------- K5: 63-tap conv, branch-free clamped global loads into VGPRs ----------------
__global__ __launch_bounds__(NTH) void k5_conv(const float* __restrict__ x,
                                               float* __restrict__ ws,
                                               float* __restrict__ mixed_out) {
  int bc = blockIdx.x;
  int b = bc >> 6;
  int t = threadIdx.x;
  __shared__ float wt[64];
  __shared__ float biasS;
  __shared__ double rda[2][4];
  if (t < 64) wt[t] = ws[OFF_EFF_W + (size_t)bc * 64 + t];
  if (t == 0) biasS = ws[OFF_EFF_B + bc];
  const float* row = x + (size_t)bc * LN;
  int l0 = t * 16;
  int g0 = l0 - 32;
  // Branch-free window load: every 4-aligned 16B chunk is fully in- or out-of-range.
  // Load from a clamped (always valid) address, multiply by in-range mask.
  float xw[80];
#pragma unroll
  for (int q = 0; q < 20; q++) {
    int idx = g0 + 4 * q;
    int idxc = idx < 0 ? 0 : (idx > LN - 4 ? LN - 4 : idx);
    float4 v = *(const float4*)(row + idxc);
    float m = (idx == idxc) ? 1.f : 0.f;
    xw[4*q]   = v.x * m;
    xw[4*q+1] = v.y * m;
    xw[4*q+2] = v.z * m;
    xw[4*q+3] = v.w * m;
  }
  __syncthreads();
  float bias = biasS;
  float acc[16];
#pragma unroll
  for (int jj = 0; jj < 16; jj++) acc[jj] = bias;
#pragma unroll
  for (int tau = 0; tau < 63; tau++) {
    float w = wt[tau];
#pragma unroll
    for (int jj = 0; jj < 16; jj++) acc[jj] = fmaf(w, xw[jj + tau + 1], acc[jj]);
  }
  double ls = 0, ls2 = 0;
#pragma unroll
  for (int jj = 0; jj < 16; jj++) { float v = acc[jj]; ls += v; ls2 += (double)v * (double)v; }
  for (int off = 32; off > 0; off >>= 1) {
    ls += __shfl_down(ls, off);
    ls2 += __shfl_down(ls2, off);
  }
  int w = t >> 6;
  if ((t & 63) == 0) { rda[0][w] = ls; rda[1][w] = ls2; }
  __syncthreads();
  if (t == 0) {
    double* gacc = (double*)(ws + OFF_GN);
    atomicAdd(&gacc[b * 2 + 0], rda[0][0]+rda[0][1]+rda[0][2]+rda[0][3]);
    atomicAdd(&gacc[b * 2 + 1], rda[1][0]+rda[1][1]+rda[1][2]+rda[1][3]);
  }
  float* dst = mixed_out + (size_t)bc * LN + l0;
#pragma unroll
  for (int q = 0; q < 4; q++) {
    float4 v; v.x = acc[4*q]; v.y = acc[4*q+1]; v.z = acc[4*q+2]; v.w = acc[4*q+3];
    *(float4*)(dst + 4 * q) = v;
  }
}

// ---------------- K6: GN + GELU + proj + residual ----------------
__global__ __launch_bounds__(NTH) void k6_final(const float* __restrict__ x,
    const float* __restrict__ proj_w, const float* __restrict__ proj_b,
    const float* __restrict__ gn_g, const float* __restrict__ gn_b,
    const float* __restrict__ res_scale,
    const float* __restrict__ ws, float* out) {
  int blk = blockIdx.x;
  int b = blk >> 5;
  int l0 = (blk & 31) * 128;
  __shared__ float actS[64 * 128];
  __shared__ float Wt[64 * 64];
  const double* gacc = (const double*)(ws + OFF_GN);
  double s1 = gacc[b * 2 + 0], s2d = gacc[b * 2 + 1];
  const double NN = 64.0 * 4096.0;
  double mud = s1 / NN;
  float mu = (float)mud;
  float var = (float)(s2d / NN - mud * mud);
  float rstd = rsqrtf(var + 1e-5f);
  for (int i = threadIdx.x; i < 4096; i += NTH) {
    int o = i & 63, c = i >> 6;
    Wt[c * 64 + o] = proj_w[o * 64 + c];
  }
  const float* mx = out + (size_t)b * CN * LN;
  for (int i = threadIdx.x; i < 8192; i += NTH) {
    int c = i >> 7, l = i & 127;
    float v = mx[(size_t)c * LN + l0 + l];
    float g = (v - mu) * rstd * gn_g[c] + gn_b[c];
    float a = 0.5f * g * (1.f + erff(g * 0.70710678118654752f));
    actS[c * 128 + l] = a;
  }
  __syncthreads();
  int lg = threadIdx.x & 31;
  int og = (threadIdx.x >> 5) * 8;
  float4 acc4[8];
#pragma unroll
  for (int q = 0; q < 8; q++) { acc4[q].x = 0.f; acc4[q].y = 0.f; acc4[q].z = 0.f; acc4[q].w = 0.f; }
  for (int c = 0; c < 64; c++) {
    float4 a = *(const float4*)&actS[c * 128 + lg * 4];
    float4 wlo = *(const float4*)&Wt[c * 64 + og];
    float4 whi = *(const float4*)&Wt[c * 64 + og + 4];
    float wv[8] = { wlo.x, wlo.y, wlo.z, wlo.w, whi.x, whi.y, whi.z, whi.w };
#pragma unroll
    for (int q = 0; q < 8; q++) {
      acc4[q].x = fmaf(wv[q], a.x, acc4[q].x);
      acc4[q].y = fmaf(wv[q], a.y, acc4[q].y);
      acc4[q].z = fmaf(wv[q], a.z, acc4[q].z);
      acc4[q].w = fmaf(wv[q], a.w, acc4[q].w);
    }
  }
  float rsv = res_scale[0];
  const float* xb = x + (size_t)b * CN * LN;
  float* ob = out + (size_t)b * CN * LN;
#pragma unroll
  for (int q = 0; q < 8; q++) {
    int o = og + q;
    float pb = proj_b[o];
    size_t base = (size_t)o * LN + l0 + lg * 4;
    float4 xv = *(const float4*)&xb[base];
    float4 r;
    r.x = xv.x + rsv * (acc4[q].x + pb);
    r.y = xv.y + rsv * (acc4[q].y + pb);
    r.z = xv.z + rsv * (acc4[q].z + pb);
    r.w = xv.w + rsv * (acc4[q].w + pb);
    *(float4*)&ob[base] = r;
  }
}

extern "C" void kernel_launch(void* const* d_in, const int* in_sizes, int n_in,
                              void* d_out, int out_size, void* d_ws, size_t ws_size,
                              hipStream_t stream) {
  const float* x        = (const float*)d_in[0];
  const float* dw7      = (const float*)d_in[1];
  const float* dw15     = (const float*)d_in[2];
  const float* dw31     = (const float*)d_in[3];
  const float* dw63     = (const float*)d_in[4];
  const float* bn_g     = (const float*)d_in[5];
  const float* bn_b     = (const float*)d_in[6];
  const float* bn_m     = (const float*)d_in[7];
  const float* bn_v     = (const float*)d_in[8];
  const float* comp_w1  = (const float*)d_in[9];
  const float* comp_b1  = (const float*)d_in[10];
  const float* comp_w2  = (const float*)d_in[11];
  const float* comp_b2  = (const float*)d_in[12];
  const float* pn_g     = (const float*)d_in[13];
  const float* pn_b     = (const float*)d_in[14];
  const float* pn_m     = (const float*)d_in[15];
  const float* pn_v     = (const float*)d_in[16];
  const float* pe_w1    = (const float*)d_in[17];
  const float* pe_b1    = (const float*)d_in[18];
  const float* pe_w2    = (const float*)d_in[19];
  const float* pe_b2    = (const float*)d_in[20];
  const float* pg_w     = (const float*)d_in[21];
  const float* pg_b     = (const float*)d_in[22];
  const float* temperature = (const float*)d_in[23];
  const float* gn_g     = (const float*)d_in[24];
  const float* gn_b     = (const float*)d_in[25];
  const float* proj_w   = (const float*)d_in[26];
  const float* proj_b   = (const float*)d_in[27];
  const float* res_scale= (const float*)d_in[28];
  float* ws = (float*)d_ws;
  float* out = (float*)d_out;

  hipLaunchKernelGGL(k0_zero, dim3(1), dim3(512), 0, stream, ws);
  hipLaunchKernelGGL(k1_chan, dim3(BQ * CN), dim3(NTH), 0, stream, x, ws);
  hipLaunchKernelGGL(kA_svm, dim3(BQ * 16), dim3(NTH), 0, stream, x, ws);
  hipLaunchKernelGGL(k3_fft, dim3(BQ * 32), dim3(NTH), 0, stream, x, ws);
  hipLaunchKernelGGL(k4_gate, dim3(BQ), dim3(NTH), 0, stream,
                     dw7, dw15, dw31, dw63, bn_g, bn_b, bn_m, bn_v,
                     comp_w1, comp_b1, comp_w2, comp_b2,
                     pn_g, pn_b, pn_m, pn_v, pe_w1, pe_b1, pe_w2, pe_b2,
                     pg_w, pg_b, temperature, ws);
  hipLaunchKernelGGL(k5_conv, dim3(BQ * CN), dim3(NTH), 0, stream, x, ws, out);
  hipLaunchKernelGGL(k6_final, dim3(BQ * 32), dim3(NTH), 0, stream,
                     x, proj_w, proj_b, gn_g, gn_b, res_scale, ws, out);
}

// Round 6
// 242.180 us; speedup vs baseline: 1.2062x; 1.1570x over previous
//
#include <hip/hip_runtime.h>
#include <math.h>

#define LN 4096
#define CN 64
#define BQ 32
#define NTH 256

// ws offsets (floats)
#define OFF_CHAN_SUM    0        // 2048
#define OFF_CHAN_JERK   2048     // 2048
#define OFF_CHAN_JRATE  4096     // 2048
#define OFF_CHAN_ZCR    6144     // 2048
#define OFF_SVMST_PART  8192     // 512 blocks * 8
#define OFF_SPEC_PART   12288    // 1024 blocks * 3
#define OFF_EFF_B       15360    // 2048
#define OFF_GNP         17408    // 2048 double pairs = 4096 floats (byte 69632 %8==0)
#define OFF_EFF_W       21504    // 2048*64
#define OFF_SVMBUF      152576   // 32*4096
// total 283648 floats = 1.13 MB

#define FP(i) ((i) + ((i) >> 4))

// ================= kS: fused k1 (row scans) + kA (svm) + k3 (fft) =================
__global__ __launch_bounds__(NTH) void kS(const float* __restrict__ x, float* __restrict__ ws) {
  __shared__ __align__(16) char smraw[34880];
  int role = blockIdx.x;
  int t = threadIdx.x;

  if (role < 2048) {
    // ---------- k1: per-(b,c) scans ----------
    int bc = role;
    const float* row = x + (size_t)bc * LN;
    int l0 = t * 16;
    float rd[18];
    const float4* r4 = (const float4*)(row + l0);
#pragma unroll
    for (int q = 0; q < 4; q++) {
      float4 v = r4[q];
      rd[4*q] = v.x; rd[4*q+1] = v.y; rd[4*q+2] = v.z; rd[4*q+3] = v.w;
    }
    if (t < 255) { rd[16] = row[l0 + 16]; rd[17] = row[l0 + 17]; }
    else { rd[16] = 0.f; rd[17] = 0.f; }
    float lsum = 0.f, jm = 0.f, jrm = 0.f; int zc = 0;
#pragma unroll
    for (int i = 0; i < 16; i++) {
      float a = rd[i], b2 = rd[i+1];
      lsum += a;
      int l = l0 + i;
      if (l < LN - 1) {
        jm = fmaxf(jm, fabsf(b2 - a));
        zc += (a * b2 < 0.f);
        if (l < LN - 2) jrm = fmaxf(jrm, fabsf(rd[i+2] - 2.f*b2 + a));
      }
    }
    for (int off = 32; off > 0; off >>= 1) {
      lsum += __shfl_down(lsum, off);
      jm = fmaxf(jm, __shfl_down(jm, off));
      jrm = fmaxf(jrm, __shfl_down(jrm, off));
      zc += __shfl_down(zc, off);
    }
    float* s1 = (float*)smraw; float* s2_ = s1 + 4; float* s3 = s1 + 8; int* s4 = (int*)(s1 + 12);
    int w = t >> 6;
    if ((t & 63) == 0) { s1[w] = lsum; s2_[w] = jm; s3[w] = jrm; s4[w] = zc; }
    __syncthreads();
    if (t == 0) {
      float S = 0, J = 0, JR = 0; int Z = 0;
      for (int i = 0; i < 4; i++) { S += s1[i]; J = fmaxf(J, s2_[i]); JR = fmaxf(JR, s3[i]); Z += s4[i]; }
      ws[OFF_CHAN_SUM + bc]   = S;
      ws[OFF_CHAN_JERK + bc]  = J * 50.f;
      ws[OFF_CHAN_JRATE + bc] = JR * 2500.f;
      ws[OFF_CHAN_ZCR + bc]   = (float)Z;
    }
  } else if (role < 2560) {
    // ---------- kA: svm + partial stats ----------
    int blk = role - 2048;           // b*16 + lt
    int b = blk >> 4, lt = blk & 15;
    int l = lt * 256 + t;
    const float* xb = x + (size_t)b * CN * LN + l;
    float acc = 0.f;
#pragma unroll
    for (int c = 0; c < CN; c++) { float v = xb[(size_t)c * LN]; acc = fmaf(v, v, acc); }
    float svm = sqrtf(acc);
    ws[OFF_SVMBUF + (size_t)b * LN + l] = svm;
    const int third = LN / 3;        // 1365
    float vS = svm, vS2 = svm * svm;
    float vS2H  = (l >= LN/2) ? svm : 0.f;
    float vS2H2 = (l >= LN/2) ? svm * svm : 0.f;
    float vPRE  = (l < third) ? svm : 0.f;
    float vPOST = (l >= 2*third) ? svm : 0.f;
    float vMX = svm;
    float vMID = (l >= third && l < 2*third) ? svm : 0.f;
    for (int off = 32; off > 0; off >>= 1) {
      vS += __shfl_down(vS, off); vS2 += __shfl_down(vS2, off);
      vS2H += __shfl_down(vS2H, off); vS2H2 += __shfl_down(vS2H2, off);
      vPRE += __shfl_down(vPRE, off); vPOST += __shfl_down(vPOST, off);
      vMX = fmaxf(vMX, __shfl_down(vMX, off));
      vMID = fmaxf(vMID, __shfl_down(vMID, off));
    }
    float (*red)[4] = (float(*)[4])smraw;
    int w = t >> 6;
    if ((t & 63) == 0) {
      red[0][w] = vS; red[1][w] = vS2; red[2][w] = vMX; red[3][w] = vS2H;
      red[4][w] = vS2H2; red[5][w] = vPRE; red[6][w] = vMID; red[7][w] = vPOST;
    }
    __syncthreads();
    if (t == 0) {
      float* sp = ws + OFF_SVMST_PART + (size_t)blk * 8;
      sp[0] = red[0][0]+red[0][1]+red[0][2]+red[0][3];
      sp[1] = red[1][0]+red[1][1]+red[1][2]+red[1][3];
      sp[2] = fmaxf(fmaxf(red[2][0],red[2][1]),fmaxf(red[2][2],red[2][3]));
      sp[3] = red[3][0]+red[3][1]+red[3][2]+red[3][3];
      sp[4] = red[4][0]+red[4][1]+red[4][2]+red[4][3];
      sp[5] = red[5][0]+red[5][1]+red[5][2]+red[5][3];
      sp[6] = fmaxf(fmaxf(red[6][0],red[6][1]),fmaxf(red[6][2],red[6][3]));
      sp[7] = red[7][0]+red[7][1]+red[7][2]+red[7][3];
    }
  } else {
    // ---------- k3: radix-4 FFT, 2 real channels packed ----------
    int blk = role - 2560;           // b*32 + cpair
    int b = blk >> 5, cp = blk & 31;
    const float* r0 = x + ((size_t)b * CN + 2 * cp) * LN;
    const float* r1 = r0 + LN;
    float2* z = (float2*)smraw;                       // FP(4096) float2 = 34816 B
    float (*red)[4] = (float(*)[4])(smraw + 34816);   // 48 B
#pragma unroll
    for (int k = 0; k < 4; k++) {
      int n4 = (k * 256 + t) * 4;
      float4 a = *(const float4*)(r0 + n4);
      float4 c = *(const float4*)(r1 + n4);
      float ar[4] = {a.x, a.y, a.z, a.w}, cr[4] = {c.x, c.y, c.z, c.w};
#pragma unroll
      for (int q = 0; q < 4; q++) {
        unsigned n = (unsigned)(n4 + q);
        unsigned br = __brev(n) >> 20;
        unsigned dr = ((br & 0x555u) << 1) | ((br & 0xAAAu) >> 1);
        z[FP(dr)] = make_float2(ar[q], cr[q]);
      }
    }
    __syncthreads();
#pragma unroll
    for (int u = 0; u < 4; u++) {
      int j = u * 256 + t;
      int i0 = 4 * j;
      float2 x0 = z[FP(i0)], x1 = z[FP(i0+1)], x2 = z[FP(i0+2)], x3 = z[FP(i0+3)];
      float ar = x0.x + x2.x, ai = x0.y + x2.y;
      float br_ = x0.x - x2.x, bi = x0.y - x2.y;
      float cr = x1.x + x3.x, ci = x1.y + x3.y;
      float dr_ = x1.x - x3.x, di = x1.y - x3.y;
      z[FP(i0)]   = make_float2(ar + cr, ai + ci);
      z[FP(i0+1)] = make_float2(br_ + di, bi - dr_);
      z[FP(i0+2)] = make_float2(ar - cr, ai - ci);
      z[FP(i0+3)] = make_float2(br_ - di, bi + dr_);
    }
    __syncthreads();
#pragma unroll
    for (int s = 1; s < 6; s++) {
      int half = 1 << (2 * s);
      float angscale = 1.0f / (float)(2 * half);
#pragma unroll
      for (int u = 0; u < 4; u++) {
        int j = u * 256 + t;
        int pos = j & (half - 1);
        int i0 = ((j >> (2 * s)) << (2 * s + 2)) + pos;
        float2 x0 = z[FP(i0)];
        float2 x1 = z[FP(i0 + half)];
        float2 x2 = z[FP(i0 + 2 * half)];
        float2 x3 = z[FP(i0 + 3 * half)];
        float sv, cv;
        sincospif((float)pos * angscale, &sv, &cv);
        float w1r = cv, w1i = -sv;
        float w2r = w1r*w1r - w1i*w1i, w2i = 2.f*w1r*w1i;
        float w3r = w2r*w1r - w2i*w1i, w3i = w2r*w1i + w2i*w1r;
        float t1r = x1.x*w1r - x1.y*w1i, t1i = x1.x*w1i + x1.y*w1r;
        float t2r = x2.x*w2r - x2.y*w2i, t2i = x2.x*w2i + x2.y*w2r;
        float t3r = x3.x*w3r - x3.y*w3i, t3i = x3.x*w3i + x3.y*w3r;
        float ar = x0.x + t2r, ai = x0.y + t2i;
        float br_ = x0.x - t2r, bi = x0.y - t2i;
        float cr = t1r + t3r, ci = t1i + t3i;
        float dr_ = t1r - t3r, di = t1i - t3i;
        z[FP(i0)]            = make_float2(ar + cr, ai + ci);
        z[FP(i0 + half)]     = make_float2(br_ + di, bi - dr_);
        z[FP(i0 + 2*half)]   = make_float2(ar - cr, ai - ci);
        z[FP(i0 + 3*half)]   = make_float2(br_ - di, bi + dr_);
      }
      __syncthreads();
    }
    float tot = 0.f, cen = 0.f, hi = 0.f;
    for (int k = t; k <= LN / 2; k += NTH) {
      float p;
      if (k == 0 || k == LN / 2) {
        float2 v = z[FP(k)];
        p = v.x * v.x + v.y * v.y;
      } else {
        float2 zk = z[FP(k)], zn = z[FP(LN - k)];
        float a1 = zk.x + zn.x, a2 = zk.y - zn.y, a3 = zk.y + zn.y, a4 = zk.x - zn.x;
        p = 0.25f * (a1*a1 + a2*a2 + a3*a3 + a4*a4);
      }
      p *= (1.0f / LN);
      tot += p;
      cen += p * ((float)k * (1.0f / (LN / 2)));
      if (k >= 820) hi += p;
    }
    for (int off = 32; off > 0; off >>= 1) {
      tot += __shfl_down(tot, off);
      cen += __shfl_down(cen, off);
      hi  += __shfl_down(hi, off);
    }
    int w = t >> 6;
    if ((t & 63) == 0) { red[0][w] = tot; red[1][w] = cen; red[2][w] = hi; }
    __syncthreads();
    if (t == 0) {
      float* sp = ws + OFF_SPEC_PART + (size_t)blk * 3;
      sp[0] = red[0][0]+red[0][1]+red[0][2]+red[0][3];
      sp[1] = red[1][0]+red[1][1]+red[1][2]+red[1][3];
      sp[2] = red[2][0]+red[2][1]+red[2][2]+red[2][3];
    }
  }
}

// ================= K4: partial reduce + threshold counts + gate MLPs + eff kernels =================
__global__ __launch_bounds__(NTH) void k4_gate(
    const float* __restrict__ dw7, const float* __restrict__ dw15,
    const float* __restrict__ dw31, const float* __restrict__ dw63,
    const float* __restrict__ bn_g, const float* __restrict__ bn_b,
    const float* __restrict__ bn_m, const float* __restrict__ bn_v,
    const float* __restrict__ comp_w1, const float* __restrict__ comp_b1,
    const float* __restrict__ comp_w2, const float* __restrict__ comp_b2,
    const float* __restrict__ pn_g, const float* __restrict__ pn_b,
    const float* __restrict__ pn_m, const float* __restrict__ pn_v,
    const float* __restrict__ pe_w1, const float* __restrict__ pe_b1,
    const float* __restrict__ pe_w2, const float* __restrict__ pe_b2,
    const float* __restrict__ pg_w, const float* __restrict__ pg_b,
    const float* __restrict__ temperature,
    float* __restrict__ ws)
{
  int b = blockIdx.x, t = threadIdx.x;
  __shared__ float sp8[16][8];
  __shared__ float sp3[32][3];
  __shared__ float stv[10];
  __shared__ float bc2[2];
  __shared__ float xm[64], h[64], pf[12], pe1v[32], pe2v[32], lgts[4], wts[4];
  __shared__ int ri[3][4], cnts[3];
  if (t < 16) {
    const float* p = ws + OFF_SVMST_PART + (size_t)(b * 16 + t) * 8;
#pragma unroll
    for (int i = 0; i < 8; i++) sp8[t][i] = p[i];
  }
  if (t >= 32 && t < 64) {
    int i = t - 32;
    const float* p = ws + OFF_SPEC_PART + (size_t)(b * 32 + i) * 3;
    sp3[i][0] = p[0]; sp3[i][1] = p[1]; sp3[i][2] = p[2];
  }
  __syncthreads();
  if (t == 0) {
    float S=0,S2=0,MX=-1e30f,S2H=0,S2H2=0,PRE=0,MID=-1e30f,POST=0;
    for (int i = 0; i < 16; i++) {
      S += sp8[i][0]; S2 += sp8[i][1]; MX = fmaxf(MX, sp8[i][2]);
      S2H += sp8[i][3]; S2H2 += sp8[i][4]; PRE += sp8[i][5];
      MID = fmaxf(MID, sp8[i][6]); POST += sp8[i][7];
    }
    float tot=0,cen=0,hi=0;
    for (int i = 0; i < 32; i++) { tot += sp3[i][0]; cen += sp3[i][1]; hi += sp3[i][2]; }
    stv[0]=S; stv[1]=S2; stv[2]=MX; stv[3]=S2H; stv[4]=S2H2;
    stv[5]=PRE; stv[6]=MID; stv[7]=POST; stv[8]=cen/(tot+1e-6f); stv[9]=hi/(tot+1e-6f);
    float mean = S * (1.f / LN);
    float var = (S2 - S * S * (1.f / LN)) * (1.f / (LN - 1));
    var = fmaxf(var, 0.f);
    bc2[0] = mean;
    bc2[1] = sqrtf(var) + 1e-6f;
  }
  __syncthreads();
  float mean = bc2[0], stde = bc2[1];
  float thr2 = mean + 2.f * stde, thr3 = mean + 3.f * stde, thrf = mean - stde;
  const float* svm = ws + OFF_SVMBUF + (size_t)b * LN;
  int c2 = 0, c3 = 0, cf = 0;
  for (int l = t; l < LN; l += NTH) {
    float v = svm[l];
    c2 += (v > thr2); c3 += (v > thr3); cf += (v < thrf);
  }
  for (int off = 32; off > 0; off >>= 1) {
    c2 += __shfl_down(c2, off); c3 += __shfl_down(c3, off); cf += __shfl_down(cf, off);
  }
  int w = t >> 6;
  if ((t & 63) == 0) { ri[0][w] = c2; ri[1][w] = c3; ri[2][w] = cf; }
  float j = 0.f, jr = 0.f, zz = 0.f;
  if (t < 64) {
    xm[t] = ws[OFF_CHAN_SUM + b * 64 + t] * (1.0f / LN);
    j  = ws[OFF_CHAN_JERK + b * 64 + t];
    jr = ws[OFF_CHAN_JRATE + b * 64 + t];
    zz = ws[OFF_CHAN_ZCR + b * 64 + t];
    for (int off = 32; off > 0; off >>= 1) {
      j += __shfl_down(j, off); jr += __shfl_down(jr, off); zz += __shfl_down(zz, off);
    }
  }
  __syncthreads();
  if (t == 0) {
    cnts[0] = ri[0][0]+ri[0][1]+ri[0][2]+ri[0][3];
    cnts[1] = ri[1][0]+ri[1][1]+ri[1][2]+ri[1][3];
    cnts[2] = ri[2][0]+ri[2][1]+ri[2][2]+ri[2][3];
    const int third = LN / 3;
    float S2H = stv[3], S2H2 = stv[4];
    float n2 = (float)(LN / 2);
    float var2 = (S2H2 - S2H * S2H / n2) / (n2 - 1.f);
    var2 = fmaxf(var2, 0.f);
    float post_still = tanhf(1.f / (sqrtf(var2) + 1e-6f));
    float pre_mean = stv[5] / (float)third;
    float post_mean = stv[7] / (float)(LN - 2 * third);
    float pk = stv[6];
    float fp = fmaxf(pk - pre_mean, 0.f) + fmaxf(pk - post_mean, 0.f);
    fp = fp / (fabsf(pk) + 1e-6f);
    pf[0] = stv[2];
    pf[1] = mean;
    pf[2] = j * (1.f / 64);
    pf[3] = jr * (1.f / 64);
    pf[4] = (zz * (1.f / 64)) * (1.f / LN);
    pf[5] = (float)cnts[0] / LN;
    pf[6] = (float)cnts[1] / LN;
    pf[7] = post_still;
    pf[8] = (float)cnts[2] / LN;
    pf[9] = stv[8];
    pf[10] = stv[9];
    pf[11] = fp;
  }
  __syncthreads();
  if (t < 12) pf[t] = (pf[t] - pn_m[t]) * rsqrtf(pn_v[t] + 1e-5f) * pn_g[t] + pn_b[t];
  __syncthreads();
  if (t < 64) {
    float hv = comp_b1[t];
    for (int i = 0; i < 64; i++) hv = fmaf(xm[i], comp_w1[i * 64 + t], hv);
    h[t] = fmaxf(hv, 0.f);
  }
  if (t < 32) {
    float v = pe_b1[t];
    for (int i = 0; i < 12; i++) v = fmaf(pf[i], pe_w1[i * 32 + t], v);
    pe1v[t] = fmaxf(v, 0.f);
  }
  __syncthreads();
  if (t < 32) {
    float v = pe_b2[t];
    for (int i = 0; i < 32; i++) v = fmaf(pe1v[i], pe_w2[i * 32 + t], v);
    pe2v[t] = fmaxf(v, 0.f);
  }
  __syncthreads();
  if (t < 4) {
    float v = comp_b2[t];
    for (int i = 0; i < 64; i++) v = fmaf(h[i], comp_w2[i * 4 + t], v);
    float g = pg_b[t];
    for (int i = 0; i < 32; i++) g = fmaf(pe2v[i], pg_w[i * 4 + t], g);
    g = 1.f / (1.f + expf(-g));
    float temp = fmaxf(temperature[0], 0.1f);
    lgts[t] = v * g / temp;
  }
  __syncthreads();
  if (t < 4) {
    float m = fmaxf(fmaxf(lgts[0], lgts[1]), fmaxf(lgts[2], lgts[3]));
    float den = expf(lgts[0]-m) + expf(lgts[1]-m) + expf(lgts[2]-m) + expf(lgts[3]-m);
    wts[t] = expf(lgts[t] - m) / den;
  }
  __syncthreads();
  if (t < 64) {
    int c = t;
    float w0 = wts[0], w1 = wts[1], w2 = wts[2], w3 = wts[3];
    float sc0 = bn_g[0*64+c] * rsqrtf(bn_v[0*64+c] + 1e-5f);
    float sc1 = bn_g[1*64+c] * rsqrtf(bn_v[1*64+c] + 1e-5f);
    float sc2 = bn_g[2*64+c] * rsqrtf(bn_v[2*64+c] + 1e-5f);
    float sc3 = bn_g[3*64+c] * rsqrtf(bn_v[3*64+c] + 1e-5f);
    float o0 = bn_b[0*64+c] - bn_m[0*64+c] * sc0;
    float o1 = bn_b[1*64+c] - bn_m[1*64+c] * sc1;
    float o2 = bn_b[2*64+c] - bn_m[2*64+c] * sc2;
    float o3 = bn_b[3*64+c] - bn_m[3*64+c] * sc3;
    ws[OFF_EFF_B + b * 64 + c] = w0*o0 + w1*o1 + w2*o2 + w3*o3;
    float a0 = w0*sc0, a1 = w1*sc1, a2 = w2*sc2, a3 = w3*sc3;
    float* eff = ws + OFF_EFF_W + (size_t)(b * 64 + c) * 64;
    for (int tau = 0; tau < 64; tau++) {
      float v = 0.f;
      if (tau < 63) {
        v = a3 * dw63[c * 63 + tau];
        int i7 = tau - 28;  if (i7 >= 0 && i7 < 7)   v = fmaf(a0, dw7[c * 7 + i7], v);
        int i15 = tau - 24; if (i15 >= 0 && i15 < 15) v = fmaf(a1, dw15[c * 15 + i15], v);
        int i31 = tau - 16; if (i31 >= 0 && i31 < 31) v = fmaf(a2, dw31[c * 31 + i31], v);
      }
      eff[tau] = v;
    }
  }
}

// ================= K5: 63-tap conv, 5-register sliding window =================
__device__ __forceinline__ float4 ldmask(const float* __restrict__ row, int idx) {
  int idxc = idx < 0 ? 0 : (idx > LN - 4 ? LN - 4 : idx);
  float4 v = *(const float4*)(row + idxc);
  float m = (idx == idxc) ? 1.f : 0.f;
  v.x *= m; v.y *= m; v.z *= m; v.w *= m;
  return v;
}

#define F16(wv,a0,a1,a2,a3,a4,a5,a6,a7,a8,a9,aA,aB,aC,aD,aE,aF) \
  acc[0]=fmaf(wv,a0,acc[0]);  acc[1]=fmaf(wv,a1,acc[1]);  acc[2]=fmaf(wv,a2,acc[2]);  acc[3]=fmaf(wv,a3,acc[3]);  \
  acc[4]=fmaf(wv,a4,acc[4]);  acc[5]=fmaf(wv,a5,acc[5]);  acc[6]=fmaf(wv,a6,acc[6]);  acc[7]=fmaf(wv,a7,acc[7]);  \
  acc[8]=fmaf(wv,a8,acc[8]);  acc[9]=fmaf(wv,a9,acc[9]);  acc[10]=fmaf(wv,aA,acc[10]); acc[11]=fmaf(wv,aB,acc[11]); \
  acc[12]=fmaf(wv,aC,acc[12]); acc[13]=fmaf(wv,aD,acc[13]); acc[14]=fmaf(wv,aE,acc[14]); acc[15]=fmaf(wv,aF,acc[15]);

__global__ __launch_bounds__(NTH) void k5_conv(const float* __restrict__ x,
                                               float* __restrict__ ws,
                                               float* __restrict__ mixed_out) {
  int bc = blockIdx.x;
  int t = threadIdx.x;
  __shared__ float wt[64];
  __shared__ float biasS;
  __shared__ double rda[2][4];
  if (t < 64) wt[t] = ws[OFF_EFF_W + (size_t)bc * 64 + t];
  if (t == 0) biasS = ws[OFF_EFF_B + bc];
  const float* row = x + (size_t)bc * LN;
  int l0 = t * 16;
  int g0 = l0 - 32;
  float4 R0 = ldmask(row, g0);
  float4 R1 = ldmask(row, g0 + 4);
  float4 R2 = ldmask(row, g0 + 8);
  float4 R3 = ldmask(row, g0 + 12);
  float4 R4 = ldmask(row, g0 + 16);
  __syncthreads();
  float bias = biasS;
  float acc[16];
#pragma unroll
  for (int jj = 0; jj < 16; jj++) acc[jj] = bias;
#pragma unroll
  for (int g = 0; g < 16; g++) {
    float w0 = wt[4*g], w1 = wt[4*g+1], w2 = wt[4*g+2], w3 = wt[4*g+3];
    F16(w0, R0.y,R0.z,R0.w,R1.x,R1.y,R1.z,R1.w,R2.x,R2.y,R2.z,R2.w,R3.x,R3.y,R3.z,R3.w,R4.x)
    F16(w1, R0.z,R0.w,R1.x,R1.y,R1.z,R1.w,R2.x,R2.y,R2.z,R2.w,R3.x,R3.y,R3.z,R3.w,R4.x,R4.y)
    F16(w2, R0.w,R1.x,R1.y,R1.z,R1.w,R2.x,R2.y,R2.z,R2.w,R3.x,R3.y,R3.z,R3.w,R4.x,R4.y,R4.z)
    F16(w3, R1.x,R1.y,R1.z,R1.w,R2.x,R2.y,R2.z,R2.w,R3.x,R3.y,R3.z,R3.w,R4.x,R4.y,R4.z,R4.w)
    if (g < 15) {
      R0 = R1; R1 = R2; R2 = R3; R3 = R4;
      R4 = ldmask(row, g0 + 4 * (g + 5));   // next group's +16 chunk (fixed: was +4 too far)
    }
  }
  double ls = 0, ls2 = 0;
#pragma unroll
  for (int jj = 0; jj < 16; jj++) { float v = acc[jj]; ls += v; ls2 += (double)v * (double)v; }
  for (int off = 32; off > 0; off >>= 1) {
    ls += __shfl_down(ls, off);
    ls2 += __shfl_down(ls2, off);
  }
  int w = t >> 6;
  if ((t & 63) == 0) { rda[0][w] = ls; rda[1][w] = ls2; }
  __syncthreads();
  if (t == 0) {
    double* gp = (double*)(ws + OFF_GNP);
    gp[2 * bc + 0] = rda[0][0]+rda[0][1]+rda[0][2]+rda[0][3];
    gp[2 * bc + 1] = rda[1][0]+rda[1][1]+rda[1][2]+rda[1][3];
  }
  float* dst = mixed_out + (size_t)bc * LN + l0;
#pragma unroll
  for (int q = 0; q < 4; q++) {
    float4 v; v.x = acc[4*q]; v.y = acc[4*q+1]; v.z = acc[4*q+2]; v.w = acc[4*q+3];
    *(float4*)(dst + 4 * q) = v;
  }
}

// ================= K6: GN-partial reduce + GN + GELU + proj + residual =================
__global__ __launch_bounds__(NTH) void k6_final(const float* __restrict__ x,
    const float* __restrict__ proj_w, const float* __restrict__ proj_b,
    const float* __restrict__ gn_g, const float* __restrict__ gn_b,
    const float* __restrict__ res_scale,
    const float* __restrict__ ws, float* out) {
  int blk = blockIdx.x;
  int b = blk >> 5;
  int l0 = (blk & 31) * 128;
  __shared__ float actS[64 * 128];
  __shared__ float Wt[64 * 64];
  __shared__ double rg[2][4];
  __shared__ float bcst[2];
  int t = threadIdx.x;
  {
    const double* gp = (const double*)(ws + OFF_GNP) + (size_t)b * CN * 2;
    double s1 = 0, s2 = 0;
    for (int i = t; i < CN; i += NTH) { s1 += gp[2*i]; s2 += gp[2*i+1]; }
    for (int off = 32; off > 0; off >>= 1) { s1 += __shfl_down(s1, off); s2 += __shfl_down(s2, off); }
    int w = t >> 6;
    if ((t & 63) == 0) { rg[0][w] = s1; rg[1][w] = s2; }
    __syncthreads();
    if (t == 0) {
      double S1 = rg[0][0]+rg[0][1]+rg[0][2]+rg[0][3];
      double S2 = rg[1][0]+rg[1][1]+rg[1][2]+rg[1][3];
      const double NN = 64.0 * 4096.0;
      double mud = S1 / NN;
      bcst[0] = (float)mud;
      bcst[1] = rsqrtf((float)(S2 / NN - mud * mud) + 1e-5f);
    }
  }
  for (int i = t; i < 4096; i += NTH) {
    int o = i & 63, c = i >> 6;
    Wt[c * 64 + o] = proj_w[o * 64 + c];
  }
  __syncthreads();
  float mu = bcst[0], rstd = bcst[1];
  const float* mx = out + (size_t)b * CN * LN;
  for (int i = t; i < 8192; i += NTH) {
    int c = i >> 7, l = i & 127;
    float v = mx[(size_t)c * LN + l0 + l];
    float g = (v - mu) * rstd * gn_g[c] + gn_b[c];
    float a = 0.5f * g * (1.f + erff(g * 0.70710678118654752f));
    actS[c * 128 + l] = a;
  }
  __syncthreads();
  int lg = t & 31;
  int og = (t >> 5) * 8;
  float4 acc4[8];
#pragma unroll
  for (int q = 0; q < 8; q++) { acc4[q].x = 0.f; acc4[q].y = 0.f; acc4[q].z = 0.f; acc4[q].w = 0.f; }
  for (int c = 0; c < 64; c++) {
    float4 a = *(const float4*)&actS[c * 128 + lg * 4];
    float4 wlo = *(const float4*)&Wt[c * 64 + og];
    float4 whi = *(const float4*)&Wt[c * 64 + og + 4];
    float wv[8] = { wlo.x, wlo.y, wlo.z, wlo.w, whi.x, whi.y, whi.z, whi.w };
#pragma unroll
    for (int q = 0; q < 8; q++) {
      acc4[q].x = fmaf(wv[q], a.x, acc4[q].x);
      acc4[q].y = fmaf(wv[q], a.y, acc4[q].y);
      acc4[q].z = fmaf(wv[q], a.z, acc4[q].z);
      acc4[q].w = fmaf(wv[q], a.w, acc4[q].w);
    }
  }
  float rsv = res_scale[0];
  const float* xb = x + (size_t)b * CN * LN;
  float* ob = out + (size_t)b * CN * LN;
#pragma unroll
  for (int q = 0; q < 8; q++) {
    int o = og + q;
    float pb = proj_b[o];
    size_t base = (size_t)o * LN + l0 + lg * 4;
    float4 xv = *(const float4*)&xb[base];
    float4 r;
    r.x = xv.x + rsv * (acc4[q].x + pb);
    r.y = xv.y + rsv * (acc4[q].y + pb);
    r.z = xv.z + rsv * (acc4[q].z + pb);
    r.w = xv.w + rsv * (acc4[q].w + pb);
    *(float4*)&ob[base] = r;
  }
}

extern "C" void kernel_launch(void* const* d_in, const int* in_sizes, int n_in,
                              void* d_out, int out_size, void* d_ws, size_t ws_size,
                              hipStream_t stream) {
  const float* x        = (const float*)d_in[0];
  const float* dw7      = (const float*)d_in[1];
  const float* dw15     = (const float*)d_in[2];
  const float* dw31     = (const float*)d_in[3];
  const float* dw63     = (const float*)d_in[4];
  const float* bn_g     = (const float*)d_in[5];
  const float* bn_b     = (const float*)d_in[6];
  const float* bn_m     = (const float*)d_in[7];
  const float* bn_v     = (const float*)d_in[8];
  const float* comp_w1  = (const float*)d_in[9];
  const float* comp_b1  = (const float*)d_in[10];
  const float* comp_w2  = (const float*)d_in[11];
  const float* comp_b2  = (const float*)d_in[12];
  const float* pn_g     = (const float*)d_in[13];
  const float* pn_b     = (const float*)d_in[14];
  const float* pn_m     = (const float*)d_in[15];
  const float* pn_v     = (const float*)d_in[16];
  const float* pe_w1    = (const float*)d_in[17];
  const float* pe_b1    = (const float*)d_in[18];
  const float* pe_w2    = (const float*)d_in[19];
  const float* pe_b2    = (const float*)d_in[20];
  const float* pg_w     = (const float*)d_in[21];
  const float* pg_b     = (const float*)d_in[22];
  const float* temperature = (const float*)d_in[23];
  const float* gn_g     = (const float*)d_in[24];
  const float* gn_b     = (const float*)d_in[25];
  const float* proj_w   = (const float*)d_in[26];
  const float* proj_b   = (const float*)d_in[27];
  const float* res_scale= (const float*)d_in[28];
  float* ws = (float*)d_ws;
  float* out = (float*)d_out;

  hipLaunchKernelGGL(kS, dim3(2048 + 512 + 1024), dim3(NTH), 0, stream, x, ws);
  hipLaunchKernelGGL(k4_gate, dim3(BQ), dim3(NTH), 0, stream,
                     dw7, dw15, dw31, dw63, bn_g, bn_b, bn_m, bn_v,
                     comp_w1, comp_b1, comp_w2, comp_b2,
                     pn_g, pn_b, pn_m, pn_v, pe_w1, pe_b1, pe_w2, pe_b2,
                     pg_w, pg_b, temperature, ws);
  hipLaunchKernelGGL(k5_conv, dim3(BQ * CN), dim3(NTH), 0, stream, x, ws, out);
  hipLaunchKernelGGL(k6_final, dim3(BQ * 32), dim3(NTH), 0, stream,
                     x, proj_w, proj_b, gn_g, gn_b, res_scale, ws, out);
}

// Round 7
// 240.731 us; speedup vs baseline: 1.2135x; 1.0060x over previous
//
#include <hip/hip_runtime.h>
#include <math.h>

#define LN 4096
#define CN 64
#define BQ 32
#define NTH 256

// ws offsets (floats)
#define OFF_CHAN_SUM    0        // 2048
#define OFF_CHAN_JERK   2048     // 2048
#define OFF_CHAN_JRATE  4096     // 2048
#define OFF_CHAN_ZCR    6144     // 2048
#define OFF_SVMST_PART  8192     // 512 blocks * 8
#define OFF_SPEC_PART   12288    // 1024 blocks * 3
#define OFF_EFF_B       15360    // 2048
#define OFF_GNP         17408    // 2048 double pairs = 4096 floats (byte 69632 %8==0)
#define OFF_EFF_W       21504    // 2048*64
#define OFF_SVMBUF      152576   // 32*4096
// total 283648 floats = 1.13 MB

#define FP(i) ((i) + ((i) >> 4))

// radix-4 DIT butterfly in place; twiddles applied to b,c,d
__device__ __forceinline__ void bfly4(float2& a, float2& b, float2& c, float2& d,
                                      float w1r, float w1i, float w2r, float w2i,
                                      float w3r, float w3i) {
  float t1r = b.x*w1r - b.y*w1i, t1i = b.x*w1i + b.y*w1r;
  float t2r = c.x*w2r - c.y*w2i, t2i = c.x*w2i + c.y*w2r;
  float t3r = d.x*w3r - d.y*w3i, t3i = d.x*w3i + d.y*w3r;
  float ar = a.x + t2r, ai = a.y + t2i;
  float br = a.x - t2r, bi = a.y - t2i;
  float cr = t1r + t3r, ci = t1i + t3i;
  float dr = t1r - t3r, di = t1i - t3i;
  a = make_float2(ar + cr, ai + ci);
  b = make_float2(br + di, bi - dr);
  c = make_float2(ar - cr, ai - ci);
  d = make_float2(br - di, bi + dr);
}

// ================= kS: fused k1 (row scans) + kA (svm) + k3 (fft) =================
__global__ __launch_bounds__(NTH) void kS(const float* __restrict__ x, float* __restrict__ ws) {
  __shared__ __align__(16) char smraw[34880];
  int role = blockIdx.x;
  int t = threadIdx.x;

  if (role < 2048) {
    // ---------- k1: per-(b,c) scans ----------
    int bc = role;
    const float* row = x + (size_t)bc * LN;
    int l0 = t * 16;
    float rd[18];
    const float4* r4 = (const float4*)(row + l0);
#pragma unroll
    for (int q = 0; q < 4; q++) {
      float4 v = r4[q];
      rd[4*q] = v.x; rd[4*q+1] = v.y; rd[4*q+2] = v.z; rd[4*q+3] = v.w;
    }
    if (t < 255) { rd[16] = row[l0 + 16]; rd[17] = row[l0 + 17]; }
    else { rd[16] = 0.f; rd[17] = 0.f; }
    float lsum = 0.f, jm = 0.f, jrm = 0.f; int zc = 0;
#pragma unroll
    for (int i = 0; i < 16; i++) {
      float a = rd[i], b2 = rd[i+1];
      lsum += a;
      int l = l0 + i;
      if (l < LN - 1) {
        jm = fmaxf(jm, fabsf(b2 - a));
        zc += (a * b2 < 0.f);
        if (l < LN - 2) jrm = fmaxf(jrm, fabsf(rd[i+2] - 2.f*b2 + a));
      }
    }
    for (int off = 32; off > 0; off >>= 1) {
      lsum += __shfl_down(lsum, off);
      jm = fmaxf(jm, __shfl_down(jm, off));
      jrm = fmaxf(jrm, __shfl_down(jrm, off));
      zc += __shfl_down(zc, off);
    }
    float* s1 = (float*)smraw; float* s2_ = s1 + 4; float* s3 = s1 + 8; int* s4 = (int*)(s1 + 12);
    int w = t >> 6;
    if ((t & 63) == 0) { s1[w] = lsum; s2_[w] = jm; s3[w] = jrm; s4[w] = zc; }
    __syncthreads();
    if (t == 0) {
      float S = 0, J = 0, JR = 0; int Z = 0;
      for (int i = 0; i < 4; i++) { S += s1[i]; J = fmaxf(J, s2_[i]); JR = fmaxf(JR, s3[i]); Z += s4[i]; }
      ws[OFF_CHAN_SUM + bc]   = S;
      ws[OFF_CHAN_JERK + bc]  = J * 50.f;
      ws[OFF_CHAN_JRATE + bc] = JR * 2500.f;
      ws[OFF_CHAN_ZCR + bc]   = (float)Z;
    }
  } else if (role < 2560) {
    // ---------- kA: svm + partial stats ----------
    int blk = role - 2048;           // b*16 + lt
    int b = blk >> 4, lt = blk & 15;
    int l = lt * 256 + t;
    const float* xb = x + (size_t)b * CN * LN + l;
    float acc = 0.f;
#pragma unroll
    for (int c = 0; c < CN; c++) { float v = xb[(size_t)c * LN]; acc = fmaf(v, v, acc); }
    float svm = sqrtf(acc);
    ws[OFF_SVMBUF + (size_t)b * LN + l] = svm;
    const int third = LN / 3;        // 1365
    float vS = svm, vS2 = svm * svm;
    float vS2H  = (l >= LN/2) ? svm : 0.f;
    float vS2H2 = (l >= LN/2) ? svm * svm : 0.f;
    float vPRE  = (l < third) ? svm : 0.f;
    float vPOST = (l >= 2*third) ? svm : 0.f;
    float vMX = svm;
    float vMID = (l >= third && l < 2*third) ? svm : 0.f;
    for (int off = 32; off > 0; off >>= 1) {
      vS += __shfl_down(vS, off); vS2 += __shfl_down(vS2, off);
      vS2H += __shfl_down(vS2H, off); vS2H2 += __shfl_down(vS2H2, off);
      vPRE += __shfl_down(vPRE, off); vPOST += __shfl_down(vPOST, off);
      vMX = fmaxf(vMX, __shfl_down(vMX, off));
      vMID = fmaxf(vMID, __shfl_down(vMID, off));
    }
    float (*red)[4] = (float(*)[4])smraw;
    int w = t >> 6;
    if ((t & 63) == 0) {
      red[0][w] = vS; red[1][w] = vS2; red[2][w] = vMX; red[3][w] = vS2H;
      red[4][w] = vS2H2; red[5][w] = vPRE; red[6][w] = vMID; red[7][w] = vPOST;
    }
    __syncthreads();
    if (t == 0) {
      float* sp = ws + OFF_SVMST_PART + (size_t)blk * 8;
      sp[0] = red[0][0]+red[0][1]+red[0][2]+red[0][3];
      sp[1] = red[1][0]+red[1][1]+red[1][2]+red[1][3];
      sp[2] = fmaxf(fmaxf(red[2][0],red[2][1]),fmaxf(red[2][2],red[2][3]));
      sp[3] = red[3][0]+red[3][1]+red[3][2]+red[3][3];
      sp[4] = red[4][0]+red[4][1]+red[4][2]+red[4][3];
      sp[5] = red[5][0]+red[5][1]+red[5][2]+red[5][3];
      sp[6] = fmaxf(fmaxf(red[6][0],red[6][1]),fmaxf(red[6][2],red[6][3]));
      sp[7] = red[7][0]+red[7][1]+red[7][2]+red[7][3];
    }
  } else {
    // ---------- k3: FFT as 3 register-resident radix-16 stages (2 real ch packed) ----------
    int blk = role - 2560;           // b*32 + cpair
    int b = blk >> 5, cp = blk & 31;
    const float* r0 = x + ((size_t)b * CN + 2 * cp) * LN;
    const float* r1 = r0 + LN;
    float2* z = (float2*)smraw;                       // FP(4096) float2 = 34816 B
    float (*red)[4] = (float(*)[4])(smraw + 34816);   // 48 B
#pragma unroll
    for (int k = 0; k < 4; k++) {
      int n4 = (k * 256 + t) * 4;
      float4 a = *(const float4*)(r0 + n4);
      float4 c = *(const float4*)(r1 + n4);
      float ar[4] = {a.x, a.y, a.z, a.w}, cr[4] = {c.x, c.y, c.z, c.w};
#pragma unroll
      for (int q = 0; q < 4; q++) {
        unsigned n = (unsigned)(n4 + q);
        unsigned br = __brev(n) >> 20;
        unsigned dr = ((br & 0x555u) << 1) | ((br & 0xAAAu) >> 1);
        z[FP(dr)] = make_float2(ar[q], cr[q]);
      }
    }
    __syncthreads();
    // exp(-i*pi*m/8), m=0..3
    const float c8r[4] = { 1.f, 0.92387953251f, 0.70710678119f, 0.38268343236f };
    const float c8i[4] = { 0.f, -0.38268343236f, -0.70710678119f, -0.92387953251f };
#pragma unroll
    for (int p = 0; p < 3; p++) {
      const int H = (p == 0) ? 1 : (p == 1) ? 16 : 256;
      int r = t & (H - 1);
      int B = ((t / H) * 16 * H) + r;
      float2 E[16];
#pragma unroll
      for (int q = 0; q < 16; q++) E[q] = z[FP(B + q * H)];
      // u = exp(-i*pi*r/(8H)); layer-1 twiddle = u^4
      float su, cu;
      sincospif((float)r / (8.0f * (float)H), &su, &cu);
      float ur = cu, ui = -su;
      float u2r = ur*ur - ui*ui, u2i = 2.f*ur*ui;
      float w1r = u2r*u2r - u2i*u2i, w1i = 2.f*u2r*u2i;      // u^4
      float w2r = w1r*w1r - w1i*w1i, w2i = 2.f*w1r*w1i;       // u^8
      float w3r = w2r*w1r - w2i*w1i, w3i = w2r*w1i + w2i*w1r; // u^12
      // layer 1: consecutive quads, same twiddles
#pragma unroll
      for (int m = 0; m < 4; m++)
        bfly4(E[4*m], E[4*m+1], E[4*m+2], E[4*m+3], w1r, w1i, w2r, w2i, w3r, w3i);
      // layer 2: strided quads, twiddle W1 = u * c8[m]
#pragma unroll
      for (int m = 0; m < 4; m++) {
        float W1r = ur*c8r[m] - ui*c8i[m];
        float W1i = ur*c8i[m] + ui*c8r[m];
        float W2r = W1r*W1r - W1i*W1i, W2i = 2.f*W1r*W1i;
        float W3r = W2r*W1r - W2i*W1i, W3i = W2r*W1i + W2i*W1r;
        bfly4(E[m], E[m+4], E[m+8], E[m+12], W1r, W1i, W2r, W2i, W3r, W3i);
      }
#pragma unroll
      for (int q = 0; q < 16; q++) z[FP(B + q * H)] = E[q];
      __syncthreads();
    }
    float tot = 0.f, cen = 0.f, hi = 0.f;
    for (int k = t; k <= LN / 2; k += NTH) {
      float p;
      if (k == 0 || k == LN / 2) {
        float2 v = z[FP(k)];
        p = v.x * v.x + v.y * v.y;
      } else {
        float2 zk = z[FP(k)], zn = z[FP(LN - k)];
        float a1 = zk.x + zn.x, a2 = zk.y - zn.y, a3 = zk.y + zn.y, a4 = zk.x - zn.x;
        p = 0.25f * (a1*a1 + a2*a2 + a3*a3 + a4*a4);
      }
      p *= (1.0f / LN);
      tot += p;
      cen += p * ((float)k * (1.0f / (LN / 2)));
      if (k >= 820) hi += p;
    }
    for (int off = 32; off > 0; off >>= 1) {
      tot += __shfl_down(tot, off);
      cen += __shfl_down(cen, off);
      hi  += __shfl_down(hi, off);
    }
    int w = t >> 6;
    if ((t & 63) == 0) { red[0][w] = tot; red[1][w] = cen; red[2][w] = hi; }
    __syncthreads();
    if (t == 0) {
      float* sp = ws + OFF_SPEC_PART + (size_t)blk * 3;
      sp[0] = red[0][0]+red[0][1]+red[0][2]+red[0][3];
      sp[1] = red[1][0]+red[1][1]+red[1][2]+red[1][3];
      sp[2] = red[2][0]+red[2][1]+red[2][2]+red[2][3];
    }
  }
}

// ================= K4: partial reduce + threshold counts + gate MLPs + eff kernels =================
__global__ __launch_bounds__(NTH) void k4_gate(
    const float* __restrict__ dw7, const float* __restrict__ dw15,
    const float* __restrict__ dw31, const float* __restrict__ dw63,
    const float* __restrict__ bn_g, const float* __restrict__ bn_b,
    const float* __restrict__ bn_m, const float* __restrict__ bn_v,
    const float* __restrict__ comp_w1, const float* __restrict__ comp_b1,
    const float* __restrict__ comp_w2, const float* __restrict__ comp_b2,
    const float* __restrict__ pn_g, const float* __restrict__ pn_b,
    const float* __restrict__ pn_m, const float* __restrict__ pn_v,
    const float* __restrict__ pe_w1, const float* __restrict__ pe_b1,
    const float* __restrict__ pe_w2, const float* __restrict__ pe_b2,
    const float* __restrict__ pg_w, const float* __restrict__ pg_b,
    const float* __restrict__ temperature,
    float* __restrict__ ws)
{
  int b = blockIdx.x, t = threadIdx.x;
  __shared__ float sp8[16][8];
  __shared__ float sp3[32][3];
  __shared__ float stv[10];
  __shared__ float bc2[2];
  __shared__ float xm[64], h[64], pf[12], pe1v[32], pe2v[32], lgts[4], wts[4];
  __shared__ int ri[3][4], cnts[3];
  if (t < 16) {
    const float* p = ws + OFF_SVMST_PART + (size_t)(b * 16 + t) * 8;
#pragma unroll
    for (int i = 0; i < 8; i++) sp8[t][i] = p[i];
  }
  if (t >= 32 && t < 64) {
    int i = t - 32;
    const float* p = ws + OFF_SPEC_PART + (size_t)(b * 32 + i) * 3;
    sp3[i][0] = p[0]; sp3[i][1] = p[1]; sp3[i][2] = p[2];
  }
  __syncthreads();
  if (t == 0) {
    float S=0,S2=0,MX=-1e30f,S2H=0,S2H2=0,PRE=0,MID=-1e30f,POST=0;
    for (int i = 0; i < 16; i++) {
      S += sp8[i][0]; S2 += sp8[i][1]; MX = fmaxf(MX, sp8[i][2]);
      S2H += sp8[i][3]; S2H2 += sp8[i][4]; PRE += sp8[i][5];
      MID = fmaxf(MID, sp8[i][6]); POST += sp8[i][7];
    }
    float tot=0,cen=0,hi=0;
    for (int i = 0; i < 32; i++) { tot += sp3[i][0]; cen += sp3[i][1]; hi += sp3[i][2]; }
    stv[0]=S; stv[1]=S2; stv[2]=MX; stv[3]=S2H; stv[4]=S2H2;
    stv[5]=PRE; stv[6]=MID; stv[7]=POST; stv[8]=cen/(tot+1e-6f); stv[9]=hi/(tot+1e-6f);
    float mean = S * (1.f / LN);
    float var = (S2 - S * S * (1.f / LN)) * (1.f / (LN - 1));
    var = fmaxf(var, 0.f);
    bc2[0] = mean;
    bc2[1] = sqrtf(var) + 1e-6f;
  }
  __syncthreads();
  float mean = bc2[0], stde = bc2[1];
  float thr2 = mean + 2.f * stde, thr3 = mean + 3.f * stde, thrf = mean - stde;
  const float* svm = ws + OFF_SVMBUF + (size_t)b * LN;
  int c2 = 0, c3 = 0, cf = 0;
  for (int l = t; l < LN; l += NTH) {
    float v = svm[l];
    c2 += (v > thr2); c3 += (v > thr3); cf += (v < thrf);
  }
  for (int off = 32; off > 0; off >>= 1) {
    c2 += __shfl_down(c2, off); c3 += __shfl_down(c3, off); cf += __shfl_down(cf, off);
  }
  int w = t >> 6;
  if ((t & 63) == 0) { ri[0][w] = c2; ri[1][w] = c3; ri[2][w] = cf; }
  float j = 0.f, jr = 0.f, zz = 0.f;
  if (t < 64) {
    xm[t] = ws[OFF_CHAN_SUM + b * 64 + t] * (1.0f / LN);
    j  = ws[OFF_CHAN_JERK + b * 64 + t];
    jr = ws[OFF_CHAN_JRATE + b * 64 + t];
    zz = ws[OFF_CHAN_ZCR + b * 64 + t];
    for (int off = 32; off > 0; off >>= 1) {
      j += __shfl_down(j, off); jr += __shfl_down(jr, off); zz += __shfl_down(zz, off);
    }
  }
  __syncthreads();
  if (t == 0) {
    cnts[0] = ri[0][0]+ri[0][1]+ri[0][2]+ri[0][3];
    cnts[1] = ri[1][0]+ri[1][1]+ri[1][2]+ri[1][3];
    cnts[2] = ri[2][0]+ri[2][1]+ri[2][2]+ri[2][3];
    const int third = LN / 3;
    float S2H = stv[3], S2H2 = stv[4];
    float n2 = (float)(LN / 2);
    float var2 = (S2H2 - S2H * S2H / n2) / (n2 - 1.f);
    var2 = fmaxf(var2, 0.f);
    float post_still = tanhf(1.f / (sqrtf(var2) + 1e-6f));
    float pre_mean = stv[5] / (float)third;
    float post_mean = stv[7] / (float)(LN - 2 * third);
    float pk = stv[6];
    float fp = fmaxf(pk - pre_mean, 0.f) + fmaxf(pk - post_mean, 0.f);
    fp = fp / (fabsf(pk) + 1e-6f);
    pf[0] = stv[2];
    pf[1] = mean;
    pf[2] = j * (1.f / 64);
    pf[3] = jr * (1.f / 64);
    pf[4] = (zz * (1.f / 64)) * (1.f / LN);
    pf[5] = (float)cnts[0] / LN;
    pf[6] = (float)cnts[1] / LN;
    pf[7] = post_still;
    pf[8] = (float)cnts[2] / LN;
    pf[9] = stv[8];
    pf[10] = stv[9];
    pf[11] = fp;
  }
  __syncthreads();
  if (t < 12) pf[t] = (pf[t] - pn_m[t]) * rsqrtf(pn_v[t] + 1e-5f) * pn_g[t] + pn_b[t];
  __syncthreads();
  if (t < 64) {
    float hv = comp_b1[t];
    for (int i = 0; i < 64; i++) hv = fmaf(xm[i], comp_w1[i * 64 + t], hv);
    h[t] = fmaxf(hv, 0.f);
  }
  if (t < 32) {
    float v = pe_b1[t];
    for (int i = 0; i < 12; i++) v = fmaf(pf[i], pe_w1[i * 32 + t], v);
    pe1v[t] = fmaxf(v, 0.f);
  }
  __syncthreads();
  if (t < 32) {
    float v = pe_b2[t];
    for (int i = 0; i < 32; i++) v = fmaf(pe1v[i], pe_w2[i * 32 + t], v);
    pe2v[t] = fmaxf(v, 0.f);
  }
  __syncthreads();
  if (t < 4) {
    float v = comp_b2[t];
    for (int i = 0; i < 64; i++) v = fmaf(h[i], comp_w2[i * 4 + t], v);
    float g = pg_b[t];
    for (int i = 0; i < 32; i++) g = fmaf(pe2v[i], pg_w[i * 4 + t], g);
    g = 1.f / (1.f + expf(-g));
    float temp = fmaxf(temperature[0], 0.1f);
    lgts[t] = v * g / temp;
  }
  __syncthreads();
  if (t < 4) {
    float m = fmaxf(fmaxf(lgts[0], lgts[1]), fmaxf(lgts[2], lgts[3]));
    float den = expf(lgts[0]-m) + expf(lgts[1]-m) + expf(lgts[2]-m) + expf(lgts[3]-m);
    wts[t] = expf(lgts[t] - m) / den;
  }
  __syncthreads();
  if (t < 64) {
    int c = t;
    float w0 = wts[0], w1 = wts[1], w2 = wts[2], w3 = wts[3];
    float sc0 = bn_g[0*64+c] * rsqrtf(bn_v[0*64+c] + 1e-5f);
    float sc1 = bn_g[1*64+c] * rsqrtf(bn_v[1*64+c] + 1e-5f);
    float sc2 = bn_g[2*64+c] * rsqrtf(bn_v[2*64+c] + 1e-5f);
    float sc3 = bn_g[3*64+c] * rsqrtf(bn_v[3*64+c] + 1e-5f);
    float o0 = bn_b[0*64+c] - bn_m[0*64+c] * sc0;
    float o1 = bn_b[1*64+c] - bn_m[1*64+c] * sc1;
    float o2 = bn_b[2*64+c] - bn_m[2*64+c] * sc2;
    float o3 = bn_b[3*64+c] - bn_m[3*64+c] * sc3;
    ws[OFF_EFF_B + b * 64 + c] = w0*o0 + w1*o1 + w2*o2 + w3*o3;
    float a0 = w0*sc0, a1 = w1*sc1, a2 = w2*sc2, a3 = w3*sc3;
    float* eff = ws + OFF_EFF_W + (size_t)(b * 64 + c) * 64;
    for (int tau = 0; tau < 64; tau++) {
      float v = 0.f;
      if (tau < 63) {
        v = a3 * dw63[c * 63 + tau];
        int i7 = tau - 28;  if (i7 >= 0 && i7 < 7)   v = fmaf(a0, dw7[c * 7 + i7], v);
        int i15 = tau - 24; if (i15 >= 0 && i15 < 15) v = fmaf(a1, dw15[c * 15 + i15], v);
        int i31 = tau - 16; if (i31 >= 0 && i31 < 31) v = fmaf(a2, dw31[c * 31 + i31], v);
      }
      eff[tau] = v;
    }
  }
}

// ================= K5: 63-tap conv, 5-register sliding window =================
__device__ __forceinline__ float4 ldmask(const float* __restrict__ row, int idx) {
  int idxc = idx < 0 ? 0 : (idx > LN - 4 ? LN - 4 : idx);
  float4 v = *(const float4*)(row + idxc);
  float m = (idx == idxc) ? 1.f : 0.f;
  v.x *= m; v.y *= m; v.z *= m; v.w *= m;
  return v;
}

#define F16(wv,a0,a1,a2,a3,a4,a5,a6,a7,a8,a9,aA,aB,aC,aD,aE,aF) \
  acc[0]=fmaf(wv,a0,acc[0]);  acc[1]=fmaf(wv,a1,acc[1]);  acc[2]=fmaf(wv,a2,acc[2]);  acc[3]=fmaf(wv,a3,acc[3]);  \
  acc[4]=fmaf(wv,a4,acc[4]);  acc[5]=fmaf(wv,a5,acc[5]);  acc[6]=fmaf(wv,a6,acc[6]);  acc[7]=fmaf(wv,a7,acc[7]);  \
  acc[8]=fmaf(wv,a8,acc[8]);  acc[9]=fmaf(wv,a9,acc[9]);  acc[10]=fmaf(wv,aA,acc[10]); acc[11]=fmaf(wv,aB,acc[11]); \
  acc[12]=fmaf(wv,aC,acc[12]); acc[13]=fmaf(wv,aD,acc[13]); acc[14]=fmaf(wv,aE,acc[14]); acc[15]=fmaf(wv,aF,acc[15]);

__global__ __launch_bounds__(NTH) void k5_conv(const float* __restrict__ x,
                                               float* __restrict__ ws,
                                               float* __restrict__ mixed_out) {
  int bc = blockIdx.x;
  int t = threadIdx.x;
  __shared__ float wt[64];
  __shared__ float biasS;
  __shared__ double rda[2][4];
  if (t < 64) wt[t] = ws[OFF_EFF_W + (size_t)bc * 64 + t];
  if (t == 0) biasS = ws[OFF_EFF_B + bc];
  const float* row = x + (size_t)bc * LN;
  int l0 = t * 16;
  int g0 = l0 - 32;
  float4 R0 = ldmask(row, g0);
  float4 R1 = ldmask(row, g0 + 4);
  float4 R2 = ldmask(row, g0 + 8);
  float4 R3 = ldmask(row, g0 + 12);
  float4 R4 = ldmask(row, g0 + 16);
  __syncthreads();
  float bias = biasS;
  float acc[16];
#pragma unroll
  for (int jj = 0; jj < 16; jj++) acc[jj] = bias;
#pragma unroll
  for (int g = 0; g < 16; g++) {
    float w0 = wt[4*g], w1 = wt[4*g+1], w2 = wt[4*g+2], w3 = wt[4*g+3];
    F16(w0, R0.y,R0.z,R0.w,R1.x,R1.y,R1.z,R1.w,R2.x,R2.y,R2.z,R2.w,R3.x,R3.y,R3.z,R3.w,R4.x)
    F16(w1, R0.z,R0.w,R1.x,R1.y,R1.z,R1.w,R2.x,R2.y,R2.z,R2.w,R3.x,R3.y,R3.z,R3.w,R4.x,R4.y)
    F16(w2, R0.w,R1.x,R1.y,R1.z,R1.w,R2.x,R2.y,R2.z,R2.w,R3.x,R3.y,R3.z,R3.w,R4.x,R4.y,R4.z)
    F16(w3, R1.x,R1.y,R1.z,R1.w,R2.x,R2.y,R2.z,R2.w,R3.x,R3.y,R3.z,R3.w,R4.x,R4.y,R4.z,R4.w)
    if (g < 15) {
      R0 = R1; R1 = R2; R2 = R3; R3 = R4;
      R4 = ldmask(row, g0 + 4 * (g + 5));   // next group's +16 chunk
    }
  }
  double ls = 0, ls2 = 0;
#pragma unroll
  for (int jj = 0; jj < 16; jj++) { float v = acc[jj]; ls += v; ls2 += (double)v * (double)v; }
  for (int off = 32; off > 0; off >>= 1) {
    ls += __shfl_down(ls, off);
    ls2 += __shfl_down(ls2, off);
  }
  int w = t >> 6;
  if ((t & 63) == 0) { rda[0][w] = ls; rda[1][w] = ls2; }
  __syncthreads();
  if (t == 0) {
    double* gp = (double*)(ws + OFF_GNP);
    gp[2 * bc + 0] = rda[0][0]+rda[0][1]+rda[0][2]+rda[0][3];
    gp[2 * bc + 1] = rda[1][0]+rda[1][1]+rda[1][2]+rda[1][3];
  }
  float* dst = mixed_out + (size_t)bc * LN + l0;
#pragma unroll
  for (int q = 0; q < 4; q++) {
    float4 v; v.x = acc[4*q]; v.y = acc[4*q+1]; v.z = acc[4*q+2]; v.w = acc[4*q+3];
    *(float4*)(dst + 4 * q) = v;
  }
}

// ================= K6: GN-partial reduce + GN + GELU + proj + residual =================
__global__ __launch_bounds__(NTH) void k6_final(const float* __restrict__ x,
    const float* __restrict__ proj_w, const float* __restrict__ proj_b,
    const float* __restrict__ gn_g, const float* __restrict__ gn_b,
    const float* __restrict__ res_scale,
    const float* __restrict__ ws, float* out) {
  int blk = blockIdx.x;
  int b = blk >> 5;
  int l0 = (blk & 31) * 128;
  __shared__ float actS[64 * 128];
  __shared__ float Wt[64 * 64];
  __shared__ double rg[2][4];
  __shared__ float bcst[2];
  int t = threadIdx.x;
  {
    const double* gp = (const double*)(ws + OFF_GNP) + (size_t)b * CN * 2;
    double s1 = 0, s2 = 0;
    for (int i = t; i < CN; i += NTH) { s1 += gp[2*i]; s2 += gp[2*i+1]; }
    for (int off = 32; off > 0; off >>= 1) { s1 += __shfl_down(s1, off); s2 += __shfl_down(s2, off); }
    int w = t >> 6;
    if ((t & 63) == 0) { rg[0][w] = s1; rg[1][w] = s2; }
    __syncthreads();
    if (t == 0) {
      double S1 = rg[0][0]+rg[0][1]+rg[0][2]+rg[0][3];
      double S2 = rg[1][0]+rg[1][1]+rg[1][2]+rg[1][3];
      const double NN = 64.0 * 4096.0;
      double mud = S1 / NN;
      bcst[0] = (float)mud;
      bcst[1] = rsqrtf((float)(S2 / NN - mud * mud) + 1e-5f);
    }
  }
  for (int i = t; i < 4096; i += NTH) {
    int o = i & 63, c = i >> 6;
    Wt[c * 64 + o] = proj_w[o * 64 + c];
  }
  __syncthreads();
  float mu = bcst[0], rstd = bcst[1];
  const float* mx = out + (size_t)b * CN * LN;
  for (int i = t; i < 8192; i += NTH) {
    int c = i >> 7, l = i & 127;
    float v = mx[(size_t)c * LN + l0 + l];
    float g = (v - mu) * rstd * gn_g[c] + gn_b[c];
    float a = 0.5f * g * (1.f + erff(g * 0.70710678118654752f));
    actS[c * 128 + l] = a;
  }
  __syncthreads();
  int lg = t & 31;
  int og = (t >> 5) * 8;
  float4 acc4[8];
#pragma unroll
  for (int q = 0; q < 8; q++) { acc4[q].x = 0.f; acc4[q].y = 0.f; acc4[q].z = 0.f; acc4[q].w = 0.f; }
  for (int c = 0; c < 64; c++) {
    float4 a = *(const float4*)&actS[c * 128 + lg * 4];
    float4 wlo = *(const float4*)&Wt[c * 64 + og];
    float4 whi = *(const float4*)&Wt[c * 64 + og + 4];
    float wv[8] = { wlo.x, wlo.y, wlo.z, wlo.w, whi.x, whi.y, whi.z, whi.w };
#pragma unroll
    for (int q = 0; q < 8; q++) {
      acc4[q].x = fmaf(wv[q], a.x, acc4[q].x);
      acc4[q].y = fmaf(wv[q], a.y, acc4[q].y);
      acc4[q].z = fmaf(wv[q], a.z, acc4[q].z);
      acc4[q].w = fmaf(wv[q], a.w, acc4[q].w);
    }
  }
  float rsv = res_scale[0];
  const float* xb = x + (size_t)b * CN * LN;
  float* ob = out + (size_t)b * CN * LN;
#pragma unroll
  for (int q = 0; q < 8; q++) {
    int o = og + q;
    float pb = proj_b[o];
    size_t base = (size_t)o * LN + l0 + lg * 4;
    float4 xv = *(const float4*)&xb[base];
    float4 r;
    r.x = xv.x + rsv * (acc4[q].x + pb);
    r.y = xv.y + rsv * (acc4[q].y + pb);
    r.z = xv.z + rsv * (acc4[q].z + pb);
    r.w = xv.w + rsv * (acc4[q].w + pb);
    *(float4*)&ob[base] = r;
  }
}

extern "C" void kernel_launch(void* const* d_in, const int* in_sizes, int n_in,
                              void* d_out, int out_size, void* d_ws, size_t ws_size,
                              hipStream_t stream) {
  const float* x        = (const float*)d_in[0];
  const float* dw7      = (const float*)d_in[1];
  const float* dw15     = (const float*)d_in[2];
  const float* dw31     = (const float*)d_in[3];
  const float* dw63     = (const float*)d_in[4];
  const float* bn_g     = (const float*)d_in[5];
  const float* bn_b     = (const float*)d_in[6];
  const float* bn_m     = (const float*)d_in[7];
  const float* bn_v     = (const float*)d_in[8];
  const float* comp_w1  = (const float*)d_in[9];
  const float* comp_b1  = (const float*)d_in[10];
  const float* comp_w2  = (const float*)d_in[11];
  const float* comp_b2  = (const float*)d_in[12];
  const float* pn_g     = (const float*)d_in[13];
  const float* pn_b     = (const float*)d_in[14];
  const float* pn_m     = (const float*)d_in[15];
  const float* pn_v     = (const float*)d_in[16];
  const float* pe_w1    = (const float*)d_in[17];
  const float* pe_b1    = (const float*)d_in[18];
  const float* pe_w2    = (const float*)d_in[19];
  const float* pe_b2    = (const float*)d_in[20];
  const float* pg_w     = (const float*)d_in[21];
  const float* pg_b     = (const float*)d_in[22];
  const float* temperature = (const float*)d_in[23];
  const float* gn_g     = (const float*)d_in[24];
  const float* gn_b     = (const float*)d_in[25];
  const float* proj_w   = (const float*)d_in[26];
  const float* proj_b   = (const float*)d_in[27];
  const float* res_scale= (const float*)d_in[28];
  float* ws = (float*)d_ws;
  float* out = (float*)d_out;

  hipLaunchKernelGGL(kS, dim3(2048 + 512 + 1024), dim3(NTH), 0, stream, x, ws);
  hipLaunchKernelGGL(k4_gate, dim3(BQ), dim3(NTH), 0, stream,
                     dw7, dw15, dw31, dw63, bn_g, bn_b, bn_m, bn_v,
                     comp_w1, comp_b1, comp_w2, comp_b2,
                     pn_g, pn_b, pn_m, pn_v, pe_w1, pe_b1, pe_w2, pe_b2,
                     pg_w, pg_b, temperature, ws);
  hipLaunchKernelGGL(k5_conv, dim3(BQ * CN), dim3(NTH), 0, stream, x, ws, out);
  hipLaunchKernelGGL(k6_final, dim3(BQ * 32), dim3(NTH), 0, stream,
                     x, proj_w, proj_b, gn_g, gn_b, res_scale, ws, out);
}